// Round 1
// baseline (1272.758 us; speedup 1.0000x reference)
//
#include <hip/hip_runtime.h>
#include <hip/hip_bf16.h>
#include <cstdint>

#define B_   8
#define CIN  64
#define DIM_ 256
#define H_   128
#define W_   128
#define HW_  (H_*W_)
#define HEADS_ 8
#define CH_  32

typedef __hip_bfloat16 bf16;

// ---------------------------------------------------------------------------
// Kernel 1: fused conv1x1(64->32chunk) + depthwise 3x3, output bf16.
// grid (8,8, B*3*8): 16x16 spatial tile, 32-channel chunk, tensor t in {q,k,v}
// ---------------------------------------------------------------------------
__global__ __launch_bounds__(256) void qkv_kernel(
    const float* __restrict__ xin, const float* __restrict__ yin, const float* __restrict__ zin,
    const float* __restrict__ Wq, const float* __restrict__ Wqd,
    const float* __restrict__ Wk, const float* __restrict__ Wkd,
    const float* __restrict__ Wv, const float* __restrict__ Wvd,
    bf16* __restrict__ qout, bf16* __restrict__ kout, bf16* __restrict__ vout)
{
    __shared__ float Wt[CIN][CH_];    // conv1x1 weights transposed [c][ch]
    __shared__ float Wd_s[CH_][9];    // depthwise weights
    __shared__ float t0[324][34];     // 18x18 halo of conv1x1 result, pad 34 (2-way max)

    const int tid = threadIdx.x;
    const int bz = blockIdx.z;
    const int b = bz / 24;
    const int rem = bz % 24;
    const int t = rem >> 3;
    const int dbase = (rem & 7) * CH_;

    const float* in = (t == 0) ? xin : (t == 1) ? yin : zin;
    const float* W1 = (t == 0) ? Wq  : (t == 1) ? Wk  : Wv;
    const float* Wd = (t == 0) ? Wqd : (t == 1) ? Wkd : Wvd;
    bf16* outp      = (t == 0) ? qout: (t == 1) ? kout: vout;

    for (int i = tid; i < CIN * CH_; i += 256) {
        int c = i >> 5, ch = i & 31;
        Wt[c][ch] = W1[(size_t)(dbase + ch) * CIN + c];
    }
    for (int i = tid; i < CH_ * 9; i += 256)
        Wd_s[i / 9][i % 9] = Wd[(size_t)(dbase + i / 9) * 9 + i % 9];
    __syncthreads();

    const int ox0 = blockIdx.x * 16 - 1;
    const int oy0 = blockIdx.y * 16 - 1;
    const float* inb = in + (size_t)b * CIN * HW_;

    // phase 1: conv1x1 for 18x18 halo pixels, 8 groups of 4 channels
    for (int it = tid; it < 324 * 8; it += 256) {
        int pix = it >> 3;
        int g = it & 7;
        int py = oy0 + pix / 18;
        int px = ox0 + pix % 18;
        float a0 = 0.f, a1 = 0.f, a2 = 0.f, a3 = 0.f;
        if (px >= 0 && px < W_ && py >= 0 && py < H_) {
            const float* ip = inb + (size_t)py * W_ + px;
            #pragma unroll 8
            for (int c = 0; c < CIN; ++c) {
                float xv = ip[(size_t)c * HW_];
                float4 w4 = *(const float4*)&Wt[c][g * 4];
                a0 = fmaf(xv, w4.x, a0);
                a1 = fmaf(xv, w4.y, a1);
                a2 = fmaf(xv, w4.z, a2);
                a3 = fmaf(xv, w4.w, a3);
            }
        }
        t0[pix][g * 4 + 0] = a0;
        t0[pix][g * 4 + 1] = a1;
        t0[pix][g * 4 + 2] = a2;
        t0[pix][g * 4 + 3] = a3;
    }
    __syncthreads();

    // phase 2: depthwise 3x3, column-sliding (16-tall column per work item)
    for (int it = tid; it < 512; it += 256) {
        int ch = it >> 4;
        int ox = it & 15;
        float w00 = Wd_s[ch][0], w01 = Wd_s[ch][1], w02 = Wd_s[ch][2];
        float w10 = Wd_s[ch][3], w11 = Wd_s[ch][4], w12 = Wd_s[ch][5];
        float w20 = Wd_s[ch][6], w21 = Wd_s[ch][7], w22 = Wd_s[ch][8];
        float h0m2 = 0.f, h0m1 = 0.f, h1m1 = 0.f;
        bf16* op = outp + ((size_t)b * DIM_ + dbase + ch) * HW_
                 + (size_t)(blockIdx.y * 16) * W_ + blockIdx.x * 16 + ox;
        #pragma unroll
        for (int y = 0; y < 18; ++y) {
            float v0 = t0[y * 18 + ox + 0][ch];
            float v1 = t0[y * 18 + ox + 1][ch];
            float v2 = t0[y * 18 + ox + 2][ch];
            float h0 = fmaf(v0, w00, fmaf(v1, w01, v2 * w02));
            float h1 = fmaf(v0, w10, fmaf(v1, w11, v2 * w12));
            float h2 = fmaf(v0, w20, fmaf(v1, w21, v2 * w22));
            if (y >= 2)
                op[(size_t)(y - 2) * W_] = __float2bfloat16(h0m2 + h1m1 + h2);
            h0m2 = h0m1; h0m1 = h0; h1m1 = h1;
        }
    }
}

// ---------------------------------------------------------------------------
// Kernel 2: raw Gram partials  S[i][j] = sum_n q_i[n] k_j[n]  + sumsq partials
// grid (8 chunks, 64 bh); block 256 = 8 n-slices x (4 ti x 8 tj)
// ---------------------------------------------------------------------------
__global__ __launch_bounds__(256) void gram_kernel(
    const bf16* __restrict__ q, const bf16* __restrict__ k,
    float* __restrict__ pgram, float* __restrict__ pssq, float* __restrict__ pssk)
{
    __shared__ float red[8][1024];
    __shared__ float redq[8][32];
    __shared__ float redk[8][32];

    const int bh = blockIdx.y;
    const int chunk = blockIdx.x;
    const int tid = threadIdx.x;
    const int slice = tid >> 5;
    const int t32 = tid & 31;
    const int ti = t32 >> 3;   // i-block of 8
    const int tj = t32 & 7;    // j-block of 4
    const int n0 = chunk * 2048 + slice * 256;

    const bf16* qp[8];
    const bf16* kp[4];
    #pragma unroll
    for (int i = 0; i < 8; ++i) qp[i] = q + ((size_t)(bh * 32 + ti * 8 + i)) * HW_ + n0;
    #pragma unroll
    for (int j = 0; j < 4; ++j) kp[j] = k + ((size_t)(bh * 32 + tj * 4 + j)) * HW_ + n0;

    float acc[8][4] = {};
    float sq[8] = {};
    float sk[4] = {};

    for (int n = 0; n < 256; n += 8) {
        uint4 qr[8], kr[4];
        #pragma unroll
        for (int i = 0; i < 8; ++i) qr[i] = *(const uint4*)(qp[i] + n);
        #pragma unroll
        for (int j = 0; j < 4; ++j) kr[j] = *(const uint4*)(kp[j] + n);
        #pragma unroll
        for (int e = 0; e < 4; ++e) {
            float ql[8], qh[8], kl[4], kh[4];
            #pragma unroll
            for (int i = 0; i < 8; ++i) {
                uint32_t w = ((const uint32_t*)&qr[i])[e];
                ql[i] = __uint_as_float(w << 16);
                qh[i] = __uint_as_float(w & 0xffff0000u);
            }
            #pragma unroll
            for (int j = 0; j < 4; ++j) {
                uint32_t w = ((const uint32_t*)&kr[j])[e];
                kl[j] = __uint_as_float(w << 16);
                kh[j] = __uint_as_float(w & 0xffff0000u);
            }
            #pragma unroll
            for (int i = 0; i < 8; ++i)
                #pragma unroll
                for (int j = 0; j < 4; ++j)
                    acc[i][j] = fmaf(ql[i], kl[j], fmaf(qh[i], kh[j], acc[i][j]));
            #pragma unroll
            for (int i = 0; i < 8; ++i) sq[i] = fmaf(ql[i], ql[i], fmaf(qh[i], qh[i], sq[i]));
            #pragma unroll
            for (int j = 0; j < 4; ++j) sk[j] = fmaf(kl[j], kl[j], fmaf(kh[j], kh[j], sk[j]));
        }
    }

    #pragma unroll
    for (int i = 0; i < 8; ++i)
        #pragma unroll
        for (int j = 0; j < 4; ++j)
            red[slice][(ti * 8 + i) * 32 + tj * 4 + j] = acc[i][j];
    if (tj == 0) {
        #pragma unroll
        for (int i = 0; i < 8; ++i) redq[slice][ti * 8 + i] = sq[i];
    }
    if (ti == 0) {
        #pragma unroll
        for (int j = 0; j < 4; ++j) redk[slice][tj * 4 + j] = sk[j];
    }
    __syncthreads();

    for (int p = tid; p < 1024; p += 256) {
        float s = 0.f;
        #pragma unroll
        for (int s8 = 0; s8 < 8; ++s8) s += red[s8][p];
        pgram[((size_t)bh * 8 + chunk) * 1024 + p] = s;
    }
    if (tid < 32) {
        float s = 0.f;
        #pragma unroll
        for (int s8 = 0; s8 < 8; ++s8) s += redq[s8][tid];
        pssq[((size_t)bh * 8 + chunk) * 32 + tid] = s;
    } else if (tid < 64) {
        int j = tid & 31;
        float s = 0.f;
        #pragma unroll
        for (int s8 = 0; s8 < 8; ++s8) s += redk[s8][j];
        pssk[((size_t)bh * 8 + chunk) * 32 + j] = s;
    }
}

// ---------------------------------------------------------------------------
// Kernel 3: reduce partials -> normalize -> softmax -> M = Wproj_h @ attn
// grid 64 (bh), block 256
// ---------------------------------------------------------------------------
__global__ __launch_bounds__(256) void softproj_kernel(
    const float* __restrict__ pgram, const float* __restrict__ pssq,
    const float* __restrict__ pssk, const float* __restrict__ Wproj,
    const float* __restrict__ temp, float* __restrict__ Mm)
{
    __shared__ float att[32][33];
    __shared__ float nq[32], nk[32];

    const int bh = blockIdx.x;
    const int h = bh & 7;
    const int b = bh >> 3;
    const int tid = threadIdx.x;

    for (int p = tid; p < 1024; p += 256) {
        float s = 0.f;
        #pragma unroll
        for (int c = 0; c < 8; ++c) s += pgram[((size_t)bh * 8 + c) * 1024 + p];
        att[p >> 5][p & 31] = s;
    }
    if (tid < 32) {
        float s = 0.f;
        #pragma unroll
        for (int c = 0; c < 8; ++c) s += pssq[((size_t)bh * 8 + c) * 32 + tid];
        nq[tid] = fmaxf(sqrtf(s), 1e-12f);
    } else if (tid < 64) {
        int i = tid & 31;
        float s = 0.f;
        #pragma unroll
        for (int c = 0; c < 8; ++c) s += pssk[((size_t)bh * 8 + c) * 32 + i];
        nk[i] = fmaxf(sqrtf(s), 1e-12f);
    }
    __syncthreads();

    const float T = temp[h];
    if (tid < 32) {
        int i = tid;
        float row[32];
        float mx = -1e30f;
        float qi = T / nq[i];
        #pragma unroll
        for (int j = 0; j < 32; ++j) {
            float v = att[i][j] * qi / nk[j];
            row[j] = v;
            mx = fmaxf(mx, v);
        }
        float s = 0.f;
        #pragma unroll
        for (int j = 0; j < 32; ++j) { float e = expf(row[j] - mx); row[j] = e; s += e; }
        float inv = 1.f / s;
        #pragma unroll
        for (int j = 0; j < 32; ++j) att[i][j] = row[j] * inv;
    }
    __syncthreads();

    // M[b][o][h*32+j] = sum_i Wproj[o][h*32+i] * attn[i][j]
    const int o = tid;
    float wp[32];
    #pragma unroll
    for (int i2 = 0; i2 < 32; i2 += 4)
        *(float4*)&wp[i2] = *(const float4*)&Wproj[(size_t)o * DIM_ + h * 32 + i2];
    float* mrow = Mm + ((size_t)b * DIM_ + o) * DIM_ + h * 32;
    #pragma unroll
    for (int j = 0; j < 32; ++j) {
        float s = 0.f;
        #pragma unroll
        for (int i = 0; i < 32; ++i) s = fmaf(wp[i], att[i][j], s);
        mrow[j] = s;
    }
}

// ---------------------------------------------------------------------------
// Kernel 4: out[b][o][pix] = sum_{k<256} M[b][o][k] v[b][k][pix]
//                          + sum_{c<192} Wfus[o][c] xyz[b][c][pix]
// grid (128 pix-tiles of 128, 4 o-tiles of 64, B)
// ---------------------------------------------------------------------------
__global__ __launch_bounds__(256) void final_kernel(
    const float* __restrict__ Mm, const bf16* __restrict__ vbuf,
    const float* __restrict__ xin, const float* __restrict__ yin,
    const float* __restrict__ zin, const float* __restrict__ Wfus,
    float* __restrict__ out)
{
    __shared__ float As[64][68];    // [k][o]
    __shared__ float Bs[64][132];   // [k][pix]

    const int tid = threadIdx.x;
    const int b = blockIdx.z;
    const int o0 = blockIdx.y * 64;
    const int pix0 = blockIdx.x * 128;
    const int to = tid >> 5;   // 0..7 -> 8 o's
    const int tp = tid & 31;   // 0..31 -> 4 pix

    float acc[8][4] = {};

    for (int kc = 0; kc < 7; ++kc) {
        // stage A (transposed)
        {
            int o = tid & 63;
            int kb = (tid >> 6) * 16;
            const float* src = (kc < 4)
                ? &Mm[((size_t)b * DIM_ + o0 + o) * DIM_ + kc * 64 + kb]
                : &Wfus[(size_t)(o0 + o) * 192 + (kc - 4) * 64 + kb];
            float tmp[16];
            #pragma unroll
            for (int u = 0; u < 4; ++u) *(float4*)&tmp[u * 4] = *(const float4*)(src + u * 4);
            #pragma unroll
            for (int jj = 0; jj < 16; ++jj) As[kb + jj][o] = tmp[jj];
        }
        // stage B
        {
            int r = tid >> 2;
            int c0 = (tid & 3) * 32;
            if (kc < 4) {
                const bf16* src = vbuf + ((size_t)b * DIM_ + kc * 64 + r) * HW_ + pix0 + c0;
                #pragma unroll
                for (int u = 0; u < 4; ++u) {
                    uint4 raw = *(const uint4*)(src + u * 8);
                    float f[8];
                    #pragma unroll
                    for (int e = 0; e < 4; ++e) {
                        uint32_t w = ((const uint32_t*)&raw)[e];
                        f[2 * e]     = __uint_as_float(w << 16);
                        f[2 * e + 1] = __uint_as_float(w & 0xffff0000u);
                    }
                    *(float4*)&Bs[r][c0 + u * 8]     = make_float4(f[0], f[1], f[2], f[3]);
                    *(float4*)&Bs[r][c0 + u * 8 + 4] = make_float4(f[4], f[5], f[6], f[7]);
                }
            } else {
                int c = kc * 64 + r - 256;
                const float* src = (c < 64)  ? (xin + ((size_t)b * CIN + c) * HW_)
                                 : (c < 128) ? (yin + ((size_t)b * CIN + (c - 64)) * HW_)
                                             : (zin + ((size_t)b * CIN + (c - 128)) * HW_);
                src += pix0 + c0;
                #pragma unroll
                for (int u = 0; u < 8; ++u)
                    *(float4*)&Bs[r][c0 + u * 4] = *(const float4*)(src + u * 4);
            }
        }
        __syncthreads();

        #pragma unroll 4
        for (int kk = 0; kk < 64; ++kk) {
            float a[8], bb[4];
            *(float4*)&a[0] = *(const float4*)&As[kk][to * 8];
            *(float4*)&a[4] = *(const float4*)&As[kk][to * 8 + 4];
            *(float4*)&bb[0] = *(const float4*)&Bs[kk][tp * 4];
            #pragma unroll
            for (int i = 0; i < 8; ++i)
                #pragma unroll
                for (int j = 0; j < 4; ++j)
                    acc[i][j] = fmaf(a[i], bb[j], acc[i][j]);
        }
        __syncthreads();
    }

    #pragma unroll
    for (int i = 0; i < 8; ++i) {
        int o = o0 + to * 8 + i;
        *(float4*)&out[((size_t)b * DIM_ + o) * HW_ + pix0 + tp * 4] =
            make_float4(acc[i][0], acc[i][1], acc[i][2], acc[i][3]);
    }
}

// ---------------------------------------------------------------------------
extern "C" void kernel_launch(void* const* d_in, const int* in_sizes, int n_in,
                              void* d_out, int out_size, void* d_ws, size_t ws_size,
                              hipStream_t stream) {
    (void)in_sizes; (void)n_in; (void)out_size; (void)ws_size;

    const float* x     = (const float*)d_in[0];
    const float* y     = (const float*)d_in[1];
    const float* z     = (const float*)d_in[2];
    const float* Wq    = (const float*)d_in[3];
    const float* Wqd   = (const float*)d_in[4];
    const float* Wk    = (const float*)d_in[5];
    const float* Wkd   = (const float*)d_in[6];
    const float* Wv    = (const float*)d_in[7];
    const float* Wvd   = (const float*)d_in[8];
    const float* Wproj = (const float*)d_in[9];
    const float* Wfus  = (const float*)d_in[10];
    const float* temp  = (const float*)d_in[11];

    const size_t QBYTES = (size_t)B_ * DIM_ * HW_ * sizeof(bf16);  // 64 MiB

    // q,k scratch lives in d_out (not read by final_kernel); v + small in ws
    bf16* qbuf = (bf16*)d_out;
    bf16* kbuf = (bf16*)((char*)d_out + QBYTES);
    bf16* vbuf = (bf16*)d_ws;
    float* pgram = (float*)((char*)d_ws + QBYTES);
    float* pssq  = pgram + 64 * 8 * 1024;
    float* pssk  = pssq + 64 * 8 * 32;
    float* Mm    = pssk + 64 * 8 * 32;

    qkv_kernel<<<dim3(8, 8, B_ * 3 * 8), 256, 0, stream>>>(
        x, y, z, Wq, Wqd, Wk, Wkd, Wv, Wvd, qbuf, kbuf, vbuf);
    gram_kernel<<<dim3(8, 64), 256, 0, stream>>>(qbuf, kbuf, pgram, pssq, pssk);
    softproj_kernel<<<64, 256, 0, stream>>>(pgram, pssq, pssk, Wproj, temp, Mm);
    final_kernel<<<dim3(128, 4, 8), 256, 0, stream>>>(Mm, vbuf, x, y, z, Wfus, (float*)d_out);
}

// Round 2
// 447.260 us; speedup vs baseline: 2.8457x; 2.8457x over previous
//
#include <hip/hip_runtime.h>
#include <cstdint>

#define B_   8
#define CIN  64
#define DIM_ 256
#define H_   128
#define W_   128
#define HW_  (H_*W_)

typedef unsigned short u16;
typedef unsigned int   u32;
typedef short short8 __attribute__((ext_vector_type(8)));
typedef float f32x4  __attribute__((ext_vector_type(4)));

__device__ __forceinline__ u16 f2bf(float f) {
    u32 u = __float_as_uint(f);
    u32 r = (u + 0x7fffu + ((u >> 16) & 1u)) >> 16;
    return (u16)r;
}
__device__ __forceinline__ float bf2f(u16 h) {
    return __uint_as_float(((u32)h) << 16);
}

// ---------------------------------------------------------------------------
// conv1x1 as bf16 MFMA GEMM: pre[b][256][HW] = W[256x64] @ in[b][64][HW]
// grid (128 px-panels, 8 b), block 256 (4 waves, each 64ch x 128px)
// LDS tiles XOR-swizzled per T2: elem (row,k8grp) at k8 ^ ((row&7)<<3)
// ---------------------------------------------------------------------------
__global__ __launch_bounds__(256) void conv_mfma_kernel(
    const float* __restrict__ in, const float* __restrict__ Wc,
    u16* __restrict__ pre)
{
    __shared__ u16 Alds[256 * 64];
    __shared__ u16 Blds[128 * 64];

    const int tid = threadIdx.x;
    const int b = blockIdx.y;
    const int px0 = blockIdx.x * 128;

    // stage A = weights [256][64] fp32 -> bf16, swizzled
    {
        const int row = tid;
        const float* wp = Wc + (size_t)row * 64;
        #pragma unroll
        for (int s = 0; s < 8; ++s) {
            float4 f0 = *(const float4*)(wp + s * 8);
            float4 f1 = *(const float4*)(wp + s * 8 + 4);
            uint4 pk;
            pk.x = f2bf(f0.x) | ((u32)f2bf(f0.y) << 16);
            pk.y = f2bf(f0.z) | ((u32)f2bf(f0.w) << 16);
            pk.z = f2bf(f1.x) | ((u32)f2bf(f1.y) << 16);
            pk.w = f2bf(f1.z) | ((u32)f2bf(f1.w) << 16);
            *(uint4*)&Alds[row * 64 + ((s * 8) ^ ((row & 7) << 3))] = pk;
        }
    }
    // stage B = in[64c][128px] -> bf16 transposed [px][64k], swizzled
    #pragma unroll
    for (int v4 = 0; v4 < 4; ++v4) {
        int it = tid + v4 * 256;
        int px = it & 127, cg = it >> 7;
        const float* sp = in + ((size_t)b * CIN + cg * 8) * HW_ + px0 + px;
        u32 wv[4];
        #pragma unroll
        for (int j = 0; j < 4; ++j) {
            float a = sp[(size_t)(2 * j) * HW_];
            float c = sp[(size_t)(2 * j + 1) * HW_];
            wv[j] = f2bf(a) | ((u32)f2bf(c) << 16);
        }
        *(uint4*)&Blds[px * 64 + ((cg * 8) ^ ((px & 7) << 3))] =
            make_uint4(wv[0], wv[1], wv[2], wv[3]);
    }
    __syncthreads();

    const int lane = tid & 63, wid = tid >> 6;
    const int g = lane >> 4, ln = lane & 15;
    const int m0 = wid * 64;
    f32x4 acc[4][8] = {};

    #pragma unroll
    for (int ks = 0; ks < 2; ++ks) {
        short8 af[4];
        #pragma unroll
        for (int fm = 0; fm < 4; ++fm) {
            int m = m0 + fm * 16 + ln;
            af[fm] = *(const short8*)&Alds[m * 64 + ((ks * 32 + g * 8) ^ ((m & 7) << 3))];
        }
        #pragma unroll
        for (int fn = 0; fn < 8; ++fn) {
            int p = fn * 16 + ln;
            short8 bf = *(const short8*)&Blds[p * 64 + ((ks * 32 + g * 8) ^ ((p & 7) << 3))];
            #pragma unroll
            for (int fm = 0; fm < 4; ++fm)
                acc[fm][fn] = __builtin_amdgcn_mfma_f32_16x16x32_bf16(af[fm], bf, acc[fm][fn], 0, 0, 0);
        }
    }

    u16* op = pre + (size_t)b * DIM_ * HW_;
    #pragma unroll
    for (int fm = 0; fm < 4; ++fm)
        #pragma unroll
        for (int fn = 0; fn < 8; ++fn)
            #pragma unroll
            for (int r = 0; r < 4; ++r) {
                int ch = m0 + fm * 16 + g * 4 + r;
                op[(size_t)ch * HW_ + px0 + fn * 16 + ln] = f2bf(acc[fm][fn][r]);
            }
}

// ---------------------------------------------------------------------------
// depthwise 3x3 bf16 -> bf16, SAME padding. grid (4 row-strips, 256 ch, 8 b)
// ---------------------------------------------------------------------------
__global__ __launch_bounds__(256) void dw_kernel(
    const u16* __restrict__ pre, const float* __restrict__ Wd,
    u16* __restrict__ dst)
{
    __shared__ u16 t0[34][144];   // cols 8..135 = px 0..127; cols 7,136 zero pads

    const int tid = threadIdx.x;
    const int y0 = blockIdx.x * 32;
    const int ch = blockIdx.y;
    const int b = blockIdx.z;
    const u16* src = pre + ((size_t)b * DIM_ + ch) * HW_;

    for (int i = tid; i < 68; i += 256)
        t0[i >> 1][(i & 1) ? 136 : 7] = 0;
    for (int i = tid; i < 544; i += 256) {
        int row = i >> 4, seg = i & 15;
        int gy = y0 - 1 + row;
        uint4 v = make_uint4(0, 0, 0, 0);
        if (gy >= 0 && gy < H_) v = *(const uint4*)(src + (size_t)gy * W_ + seg * 8);
        *(uint4*)&t0[row][8 + seg * 8] = v;
    }
    const float* wv = Wd + (size_t)ch * 9;
    float w00 = wv[0], w01 = wv[1], w02 = wv[2];
    float w10 = wv[3], w11 = wv[4], w12 = wv[5];
    float w20 = wv[6], w21 = wv[7], w22 = wv[8];
    __syncthreads();

    const int px = tid & 127, half = tid >> 7;
    u16* op = dst + ((size_t)b * DIM_ + ch) * HW_;
    float h0m2 = 0.f, h0m1 = 0.f, h1m1 = 0.f;
    #pragma unroll
    for (int y = 0; y < 18; ++y) {
        int r = half * 16 + y;
        float v0 = bf2f(t0[r][7 + px]);
        float v1 = bf2f(t0[r][8 + px]);
        float v2 = bf2f(t0[r][9 + px]);
        float h0 = fmaf(v0, w00, fmaf(v1, w01, v2 * w02));
        float h1 = fmaf(v0, w10, fmaf(v1, w11, v2 * w12));
        float h2 = fmaf(v0, w20, fmaf(v1, w21, v2 * w22));
        if (y >= 2)
            op[(size_t)(y0 + half * 16 + y - 2) * W_ + px] = f2bf(h0m2 + h1m1 + h2);
        h0m2 = h0m1; h0m1 = h0; h1m1 = h1;
    }
}

// ---------------------------------------------------------------------------
// Kernel: raw Gram partials + sumsq partials (unchanged from passing round)
// ---------------------------------------------------------------------------
__global__ __launch_bounds__(256) void gram_kernel(
    const u16* __restrict__ q, const u16* __restrict__ k,
    float* __restrict__ pgram, float* __restrict__ pssq, float* __restrict__ pssk)
{
    __shared__ float red[8][1024];
    __shared__ float redq[8][32];
    __shared__ float redk[8][32];

    const int bh = blockIdx.y;
    const int chunk = blockIdx.x;
    const int tid = threadIdx.x;
    const int slice = tid >> 5;
    const int t32 = tid & 31;
    const int ti = t32 >> 3;
    const int tj = t32 & 7;
    const int n0 = chunk * 2048 + slice * 256;

    const u16* qp[8];
    const u16* kp[4];
    #pragma unroll
    for (int i = 0; i < 8; ++i) qp[i] = q + ((size_t)(bh * 32 + ti * 8 + i)) * HW_ + n0;
    #pragma unroll
    for (int j = 0; j < 4; ++j) kp[j] = k + ((size_t)(bh * 32 + tj * 4 + j)) * HW_ + n0;

    float acc[8][4] = {};
    float sq[8] = {};
    float sk[4] = {};

    for (int n = 0; n < 256; n += 8) {
        uint4 qr[8], kr[4];
        #pragma unroll
        for (int i = 0; i < 8; ++i) qr[i] = *(const uint4*)(qp[i] + n);
        #pragma unroll
        for (int j = 0; j < 4; ++j) kr[j] = *(const uint4*)(kp[j] + n);
        #pragma unroll
        for (int e = 0; e < 4; ++e) {
            float ql[8], qh[8], kl[4], kh[4];
            #pragma unroll
            for (int i = 0; i < 8; ++i) {
                u32 w = ((const u32*)&qr[i])[e];
                ql[i] = __uint_as_float(w << 16);
                qh[i] = __uint_as_float(w & 0xffff0000u);
            }
            #pragma unroll
            for (int j = 0; j < 4; ++j) {
                u32 w = ((const u32*)&kr[j])[e];
                kl[j] = __uint_as_float(w << 16);
                kh[j] = __uint_as_float(w & 0xffff0000u);
            }
            #pragma unroll
            for (int i = 0; i < 8; ++i)
                #pragma unroll
                for (int j = 0; j < 4; ++j)
                    acc[i][j] = fmaf(ql[i], kl[j], fmaf(qh[i], kh[j], acc[i][j]));
            #pragma unroll
            for (int i = 0; i < 8; ++i) sq[i] = fmaf(ql[i], ql[i], fmaf(qh[i], qh[i], sq[i]));
            #pragma unroll
            for (int j = 0; j < 4; ++j) sk[j] = fmaf(kl[j], kl[j], fmaf(kh[j], kh[j], sk[j]));
        }
    }

    #pragma unroll
    for (int i = 0; i < 8; ++i)
        #pragma unroll
        for (int j = 0; j < 4; ++j)
            red[slice][(ti * 8 + i) * 32 + tj * 4 + j] = acc[i][j];
    if (tj == 0) {
        #pragma unroll
        for (int i = 0; i < 8; ++i) redq[slice][ti * 8 + i] = sq[i];
    }
    if (ti == 0) {
        #pragma unroll
        for (int j = 0; j < 4; ++j) redk[slice][tj * 4 + j] = sk[j];
    }
    __syncthreads();

    for (int p = tid; p < 1024; p += 256) {
        float s = 0.f;
        #pragma unroll
        for (int s8 = 0; s8 < 8; ++s8) s += red[s8][p];
        pgram[((size_t)bh * 8 + chunk) * 1024 + p] = s;
    }
    if (tid < 32) {
        float s = 0.f;
        #pragma unroll
        for (int s8 = 0; s8 < 8; ++s8) s += redq[s8][tid];
        pssq[((size_t)bh * 8 + chunk) * 32 + tid] = s;
    } else if (tid < 64) {
        int j = tid & 31;
        float s = 0.f;
        #pragma unroll
        for (int s8 = 0; s8 < 8; ++s8) s += redk[s8][j];
        pssk[((size_t)bh * 8 + chunk) * 32 + j] = s;
    }
}

// ---------------------------------------------------------------------------
// reduce partials -> normalize -> softmax -> M = Wproj_h @ attn (unchanged)
// ---------------------------------------------------------------------------
__global__ __launch_bounds__(256) void softproj_kernel(
    const float* __restrict__ pgram, const float* __restrict__ pssq,
    const float* __restrict__ pssk, const float* __restrict__ Wproj,
    const float* __restrict__ temp, float* __restrict__ Mm)
{
    __shared__ float att[32][33];
    __shared__ float nq[32], nk[32];

    const int bh = blockIdx.x;
    const int h = bh & 7;
    const int b = bh >> 3;
    const int tid = threadIdx.x;

    for (int p = tid; p < 1024; p += 256) {
        float s = 0.f;
        #pragma unroll
        for (int c = 0; c < 8; ++c) s += pgram[((size_t)bh * 8 + c) * 1024 + p];
        att[p >> 5][p & 31] = s;
    }
    if (tid < 32) {
        float s = 0.f;
        #pragma unroll
        for (int c = 0; c < 8; ++c) s += pssq[((size_t)bh * 8 + c) * 32 + tid];
        nq[tid] = fmaxf(sqrtf(s), 1e-12f);
    } else if (tid < 64) {
        int i = tid & 31;
        float s = 0.f;
        #pragma unroll
        for (int c = 0; c < 8; ++c) s += pssk[((size_t)bh * 8 + c) * 32 + i];
        nk[i] = fmaxf(sqrtf(s), 1e-12f);
    }
    __syncthreads();

    const float T = temp[h];
    if (tid < 32) {
        int i = tid;
        float row[32];
        float mx = -1e30f;
        float qi = T / nq[i];
        #pragma unroll
        for (int j = 0; j < 32; ++j) {
            float v = att[i][j] * qi / nk[j];
            row[j] = v;
            mx = fmaxf(mx, v);
        }
        float s = 0.f;
        #pragma unroll
        for (int j = 0; j < 32; ++j) { float e = expf(row[j] - mx); row[j] = e; s += e; }
        float inv = 1.f / s;
        #pragma unroll
        for (int j = 0; j < 32; ++j) att[i][j] = row[j] * inv;
    }
    __syncthreads();

    const int o = tid;
    float wp[32];
    #pragma unroll
    for (int i2 = 0; i2 < 32; i2 += 4)
        *(float4*)&wp[i2] = *(const float4*)&Wproj[(size_t)o * DIM_ + h * 32 + i2];
    float* mrow = Mm + ((size_t)b * DIM_ + o) * DIM_ + h * 32;
    #pragma unroll
    for (int j = 0; j < 32; ++j) {
        float s = 0.f;
        #pragma unroll
        for (int i = 0; i < 32; ++i) s = fmaf(wp[i], att[i][j], s);
        mrow[j] = s;
    }
}

// ---------------------------------------------------------------------------
// final: out[b][o][pix] = sum_{k<256} M[b][o][k] v[k][pix]
//                       + sum_{c<192} Wfus[o][c] xyz[c][pix]   (bf16 MFMA)
// grid (128 px-panels, 8 b), block 256
// ---------------------------------------------------------------------------
__global__ __launch_bounds__(256) void final_mfma_kernel(
    const float* __restrict__ Mm, const u16* __restrict__ vbuf,
    const float* __restrict__ xin, const float* __restrict__ yin,
    const float* __restrict__ zin, const float* __restrict__ Wfus,
    float* __restrict__ out)
{
    __shared__ u16 Alds[256 * 64];
    __shared__ u16 Blds[128 * 64];

    const int tid = threadIdx.x;
    const int b = blockIdx.y;
    const int px0 = blockIdx.x * 128;
    const int lane = tid & 63, wid = tid >> 6;
    const int g = lane >> 4, ln = lane & 15;
    const int m0 = wid * 64;
    f32x4 acc[4][8] = {};

    for (int kc = 0; kc < 7; ++kc) {
        // stage A chunk [256][64] -> bf16 swizzled
        {
            const int row = tid;
            const float* ap = (kc < 4)
                ? Mm + ((size_t)b * DIM_ + row) * DIM_ + kc * 64
                : Wfus + (size_t)row * 192 + (kc - 4) * 64;
            #pragma unroll
            for (int s = 0; s < 8; ++s) {
                float4 f0 = *(const float4*)(ap + s * 8);
                float4 f1 = *(const float4*)(ap + s * 8 + 4);
                uint4 pk;
                pk.x = f2bf(f0.x) | ((u32)f2bf(f0.y) << 16);
                pk.y = f2bf(f0.z) | ((u32)f2bf(f0.w) << 16);
                pk.z = f2bf(f1.x) | ((u32)f2bf(f1.y) << 16);
                pk.w = f2bf(f1.z) | ((u32)f2bf(f1.w) << 16);
                *(uint4*)&Alds[row * 64 + ((s * 8) ^ ((row & 7) << 3))] = pk;
            }
        }
        // stage B chunk -> [px][64k] bf16 swizzled
        if (kc < 4) {
            const u16* vb = vbuf + ((size_t)b * DIM_ + kc * 64) * HW_ + px0;
            #pragma unroll
            for (int v4 = 0; v4 < 4; ++v4) {
                int it = tid + v4 * 256;
                int px = it & 127, cg = it >> 7;
                const u16* sp = vb + (size_t)(cg * 8) * HW_ + px;
                u32 wv[4];
                #pragma unroll
                for (int j = 0; j < 4; ++j)
                    wv[j] = (u32)sp[(size_t)(2 * j) * HW_] | ((u32)sp[(size_t)(2 * j + 1) * HW_] << 16);
                *(uint4*)&Blds[px * 64 + ((cg * 8) ^ ((px & 7) << 3))] =
                    make_uint4(wv[0], wv[1], wv[2], wv[3]);
            }
        } else {
            const float* src = (kc == 4) ? xin : (kc == 5) ? yin : zin;
            src += (size_t)b * CIN * HW_ + px0;
            #pragma unroll
            for (int v4 = 0; v4 < 4; ++v4) {
                int it = tid + v4 * 256;
                int px = it & 127, cg = it >> 7;
                const float* sp = src + (size_t)(cg * 8) * HW_ + px;
                u32 wv[4];
                #pragma unroll
                for (int j = 0; j < 4; ++j) {
                    float a = sp[(size_t)(2 * j) * HW_];
                    float c = sp[(size_t)(2 * j + 1) * HW_];
                    wv[j] = f2bf(a) | ((u32)f2bf(c) << 16);
                }
                *(uint4*)&Blds[px * 64 + ((cg * 8) ^ ((px & 7) << 3))] =
                    make_uint4(wv[0], wv[1], wv[2], wv[3]);
            }
        }
        __syncthreads();

        #pragma unroll
        for (int ks = 0; ks < 2; ++ks) {
            short8 af[4];
            #pragma unroll
            for (int fm = 0; fm < 4; ++fm) {
                int m = m0 + fm * 16 + ln;
                af[fm] = *(const short8*)&Alds[m * 64 + ((ks * 32 + g * 8) ^ ((m & 7) << 3))];
            }
            #pragma unroll
            for (int fn = 0; fn < 8; ++fn) {
                int p = fn * 16 + ln;
                short8 bf = *(const short8*)&Blds[p * 64 + ((ks * 32 + g * 8) ^ ((p & 7) << 3))];
                #pragma unroll
                for (int fm = 0; fm < 4; ++fm)
                    acc[fm][fn] = __builtin_amdgcn_mfma_f32_16x16x32_bf16(af[fm], bf, acc[fm][fn], 0, 0, 0);
            }
        }
        __syncthreads();
    }

    float* op = out + (size_t)b * DIM_ * HW_;
    #pragma unroll
    for (int fm = 0; fm < 4; ++fm)
        #pragma unroll
        for (int fn = 0; fn < 8; ++fn)
            #pragma unroll
            for (int r = 0; r < 4; ++r) {
                int ch = m0 + fm * 16 + g * 4 + r;
                op[(size_t)ch * HW_ + px0 + fn * 16 + ln] = acc[fm][fn][r];
            }
}

// ---------------------------------------------------------------------------
extern "C" void kernel_launch(void* const* d_in, const int* in_sizes, int n_in,
                              void* d_out, int out_size, void* d_ws, size_t ws_size,
                              hipStream_t stream) {
    (void)in_sizes; (void)n_in; (void)out_size; (void)ws_size;

    const float* x     = (const float*)d_in[0];
    const float* y     = (const float*)d_in[1];
    const float* z     = (const float*)d_in[2];
    const float* Wq    = (const float*)d_in[3];
    const float* Wqd   = (const float*)d_in[4];
    const float* Wk    = (const float*)d_in[5];
    const float* Wkd   = (const float*)d_in[6];
    const float* Wv    = (const float*)d_in[7];
    const float* Wvd   = (const float*)d_in[8];
    const float* Wproj = (const float*)d_in[9];
    const float* Wfus  = (const float*)d_in[10];
    const float* temp  = (const float*)d_in[11];

    const size_t QELEMS = (size_t)B_ * DIM_ * HW_;   // 33.5M elems, 64 MiB bf16

    // d_out (128 MiB) = two 64 MiB slots: D0 = pre scratch, D1 = q
    u16* preb = (u16*)d_out;
    u16* qbuf = (u16*)d_out + QELEMS;
    // ws: W0 = k then v (64 MiB), then small fp32 arrays (~4.3 MiB)
    u16* kvbuf = (u16*)d_ws;
    float* pgram = (float*)((char*)d_ws + QELEMS * sizeof(u16));
    float* pssq  = pgram + 64 * 8 * 1024;
    float* pssk  = pssq + 64 * 8 * 32;
    float* Mm    = pssk + 64 * 8 * 32;

    dim3 cgrid(128, B_);
    dim3 dgrid(4, DIM_, B_);

    conv_mfma_kernel<<<cgrid, 256, 0, stream>>>(x, Wq, preb);
    dw_kernel<<<dgrid, 256, 0, stream>>>(preb, Wqd, qbuf);
    conv_mfma_kernel<<<cgrid, 256, 0, stream>>>(y, Wk, preb);
    dw_kernel<<<dgrid, 256, 0, stream>>>(preb, Wkd, kvbuf);
    gram_kernel<<<dim3(8, 64), 256, 0, stream>>>(qbuf, kvbuf, pgram, pssq, pssk);
    softproj_kernel<<<64, 256, 0, stream>>>(pgram, pssq, pssk, Wproj, temp, Mm);
    conv_mfma_kernel<<<cgrid, 256, 0, stream>>>(z, Wv, preb);
    dw_kernel<<<dgrid, 256, 0, stream>>>(preb, Wvd, kvbuf);
    final_mfma_kernel<<<cgrid, 256, 0, stream>>>(Mm, kvbuf, x, y, z, Wfus, (float*)d_out);
}

// Round 3
// 322.614 us; speedup vs baseline: 3.9451x; 1.3864x over previous
//
#include <hip/hip_runtime.h>
#include <cstdint>

#define B_   8
#define CIN  64
#define DIM_ 256
#define H_   128
#define W_   128
#define HW_  (H_*W_)

typedef unsigned short u16;
typedef unsigned int   u32;
typedef short short8 __attribute__((ext_vector_type(8)));
typedef float f32x4  __attribute__((ext_vector_type(4)));

__device__ __forceinline__ u16 f2bf(float f) {
    u32 u = __float_as_uint(f);
    u32 r = (u + 0x7fffu + ((u >> 16) & 1u)) >> 16;
    return (u16)r;
}
__device__ __forceinline__ float bf2f(u16 h) {
    return __uint_as_float(((u32)h) << 16);
}

// ---------------------------------------------------------------------------
// conv1x1 as bf16 MFMA GEMM: pre[b][256][HW] = W[256x64] @ in[b][64][HW]
// grid (128 px-panels, 8 b), block 256 (4 waves, each 64ch x 128px)
// ---------------------------------------------------------------------------
__global__ __launch_bounds__(256) void conv_mfma_kernel(
    const float* __restrict__ in, const float* __restrict__ Wc,
    u16* __restrict__ pre)
{
    __shared__ u16 Alds[256 * 64];
    __shared__ u16 Blds[128 * 64];

    const int tid = threadIdx.x;
    const int b = blockIdx.y;
    const int px0 = blockIdx.x * 128;

    // stage A = weights [256][64] fp32 -> bf16, swizzled
    {
        const int row = tid;
        const float* wp = Wc + (size_t)row * 64;
        #pragma unroll
        for (int s = 0; s < 8; ++s) {
            float4 f0 = *(const float4*)(wp + s * 8);
            float4 f1 = *(const float4*)(wp + s * 8 + 4);
            uint4 pk;
            pk.x = f2bf(f0.x) | ((u32)f2bf(f0.y) << 16);
            pk.y = f2bf(f0.z) | ((u32)f2bf(f0.w) << 16);
            pk.z = f2bf(f1.x) | ((u32)f2bf(f1.y) << 16);
            pk.w = f2bf(f1.z) | ((u32)f2bf(f1.w) << 16);
            *(uint4*)&Alds[row * 64 + ((s * 8) ^ ((row & 7) << 3))] = pk;
        }
    }
    // stage B = in[64c][128px] -> bf16 transposed [px][64k], swizzled
    #pragma unroll
    for (int v4 = 0; v4 < 4; ++v4) {
        int it = tid + v4 * 256;
        int px = it & 127, cg = it >> 7;
        const float* sp = in + ((size_t)b * CIN + cg * 8) * HW_ + px0 + px;
        u32 wv[4];
        #pragma unroll
        for (int j = 0; j < 4; ++j) {
            float a = sp[(size_t)(2 * j) * HW_];
            float c = sp[(size_t)(2 * j + 1) * HW_];
            wv[j] = f2bf(a) | ((u32)f2bf(c) << 16);
        }
        *(uint4*)&Blds[px * 64 + ((cg * 8) ^ ((px & 7) << 3))] =
            make_uint4(wv[0], wv[1], wv[2], wv[3]);
    }
    __syncthreads();

    const int lane = tid & 63, wid = tid >> 6;
    const int g = lane >> 4, ln = lane & 15;
    const int m0 = wid * 64;
    f32x4 acc[4][8] = {};

    #pragma unroll
    for (int ks = 0; ks < 2; ++ks) {
        short8 af[4];
        #pragma unroll
        for (int fm = 0; fm < 4; ++fm) {
            int m = m0 + fm * 16 + ln;
            af[fm] = *(const short8*)&Alds[m * 64 + ((ks * 32 + g * 8) ^ ((m & 7) << 3))];
        }
        #pragma unroll
        for (int fn = 0; fn < 8; ++fn) {
            int p = fn * 16 + ln;
            short8 bf = *(const short8*)&Blds[p * 64 + ((ks * 32 + g * 8) ^ ((p & 7) << 3))];
            #pragma unroll
            for (int fm = 0; fm < 4; ++fm)
                acc[fm][fn] = __builtin_amdgcn_mfma_f32_16x16x32_bf16(af[fm], bf, acc[fm][fn], 0, 0, 0);
        }
    }

    u16* op = pre + (size_t)b * DIM_ * HW_;
    #pragma unroll
    for (int fm = 0; fm < 4; ++fm)
        #pragma unroll
        for (int fn = 0; fn < 8; ++fn)
            #pragma unroll
            for (int r = 0; r < 4; ++r) {
                int ch = m0 + fm * 16 + g * 4 + r;
                op[(size_t)ch * HW_ + px0 + fn * 16 + ln] = f2bf(acc[fm][fn][r]);
            }
}

// ---------------------------------------------------------------------------
// depthwise 3x3 bf16 -> bf16, SAME padding. grid (4 row-strips, 256 ch, 8 b)
// ---------------------------------------------------------------------------
__global__ __launch_bounds__(256) void dw_kernel(
    const u16* __restrict__ pre, const float* __restrict__ Wd,
    u16* __restrict__ dst)
{
    __shared__ u16 t0[34][144];   // cols 8..135 = px 0..127; cols 7,136 zero pads

    const int tid = threadIdx.x;
    const int y0 = blockIdx.x * 32;
    const int ch = blockIdx.y;
    const int b = blockIdx.z;
    const u16* src = pre + ((size_t)b * DIM_ + ch) * HW_;

    for (int i = tid; i < 68; i += 256)
        t0[i >> 1][(i & 1) ? 136 : 7] = 0;
    for (int i = tid; i < 544; i += 256) {
        int row = i >> 4, seg = i & 15;
        int gy = y0 - 1 + row;
        uint4 v = make_uint4(0, 0, 0, 0);
        if (gy >= 0 && gy < H_) v = *(const uint4*)(src + (size_t)gy * W_ + seg * 8);
        *(uint4*)&t0[row][8 + seg * 8] = v;
    }
    const float* wv = Wd + (size_t)ch * 9;
    float w00 = wv[0], w01 = wv[1], w02 = wv[2];
    float w10 = wv[3], w11 = wv[4], w12 = wv[5];
    float w20 = wv[6], w21 = wv[7], w22 = wv[8];
    __syncthreads();

    const int px = tid & 127, half = tid >> 7;
    u16* op = dst + ((size_t)b * DIM_ + ch) * HW_;
    float h0m2 = 0.f, h0m1 = 0.f, h1m1 = 0.f;
    #pragma unroll
    for (int y = 0; y < 18; ++y) {
        int r = half * 16 + y;
        float v0 = bf2f(t0[r][7 + px]);
        float v1 = bf2f(t0[r][8 + px]);
        float v2 = bf2f(t0[r][9 + px]);
        float h0 = fmaf(v0, w00, fmaf(v1, w01, v2 * w02));
        float h1 = fmaf(v0, w10, fmaf(v1, w11, v2 * w12));
        float h2 = fmaf(v0, w20, fmaf(v1, w21, v2 * w22));
        if (y >= 2)
            op[(size_t)(y0 + half * 16 + y - 2) * W_ + px] = f2bf(h0m2 + h1m1 + h2);
        h0m2 = h0m1; h0m1 = h0; h1m1 = h1;
    }
}

// ---------------------------------------------------------------------------
// Gram via MFMA: per (chunk, bh), wave w covers n-slice of 512.
// A-frag = Q rows, B-frag = K rows (identical load pattern: lane(g,ln) reads
// 8 contiguous bf16 at row ln(+16), offset g*8 — 16 rows x 64B, no dup).
// Row sumsq = diagonals of mfma(qf,qf) / mfma(kf,kf) on the same fragments.
// grid (8 chunks, 64 bh), block 256.
// ---------------------------------------------------------------------------
__global__ __launch_bounds__(256) void gram_mfma_kernel(
    const u16* __restrict__ q, const u16* __restrict__ k,
    float* __restrict__ pgram, float* __restrict__ pssq, float* __restrict__ pssk)
{
    __shared__ float red[4][1024];
    __shared__ float redq[4][32];
    __shared__ float redk[4][32];

    const int bh = blockIdx.y;
    const int chunk = blockIdx.x;
    const int tid = threadIdx.x;
    const int lane = tid & 63, wid = tid >> 6;
    const int g = lane >> 4, ln = lane & 15;

    const size_t off = (size_t)(bh * 32 + ln) * HW_ + chunk * 2048 + wid * 512 + g * 8;
    const u16* qp = q + off;
    const u16* kp = k + off;

    f32x4 aqk[2][2] = {};
    f32x4 aqq[2] = {};
    f32x4 akk[2] = {};

    #pragma unroll 4
    for (int n = 0; n < 512; n += 32) {
        short8 qf[2], kf[2];
        qf[0] = *(const short8*)(qp + n);
        qf[1] = *(const short8*)(qp + (size_t)16 * HW_ + n);
        kf[0] = *(const short8*)(kp + n);
        kf[1] = *(const short8*)(kp + (size_t)16 * HW_ + n);
        #pragma unroll
        for (int ti = 0; ti < 2; ++ti)
            #pragma unroll
            for (int tj = 0; tj < 2; ++tj)
                aqk[ti][tj] = __builtin_amdgcn_mfma_f32_16x16x32_bf16(qf[ti], kf[tj], aqk[ti][tj], 0, 0, 0);
        #pragma unroll
        for (int ti = 0; ti < 2; ++ti) {
            aqq[ti] = __builtin_amdgcn_mfma_f32_16x16x32_bf16(qf[ti], qf[ti], aqq[ti], 0, 0, 0);
            akk[ti] = __builtin_amdgcn_mfma_f32_16x16x32_bf16(kf[ti], kf[ti], akk[ti], 0, 0, 0);
        }
    }

    // scatter qk partials: D row = ti*16 + g*4 + r, col = tj*16 + ln
    #pragma unroll
    for (int ti = 0; ti < 2; ++ti)
        #pragma unroll
        for (int tj = 0; tj < 2; ++tj)
            #pragma unroll
            for (int r = 0; r < 4; ++r)
                red[wid][(ti * 16 + g * 4 + r) * 32 + tj * 16 + ln] = aqk[ti][tj][r];
    // diagonals: lane holds rows g*4..g*4+3, col ln -> diag iff (ln>>2)==g
    if ((ln >> 2) == g) {
        #pragma unroll
        for (int ti = 0; ti < 2; ++ti) {
            redq[wid][ti * 16 + ln] = aqq[ti][ln & 3];
            redk[wid][ti * 16 + ln] = akk[ti][ln & 3];
        }
    }
    __syncthreads();

    for (int p = tid; p < 1024; p += 256) {
        float s = red[0][p] + red[1][p] + red[2][p] + red[3][p];
        pgram[((size_t)bh * 8 + chunk) * 1024 + p] = s;
    }
    if (tid < 32) {
        pssq[((size_t)bh * 8 + chunk) * 32 + tid] =
            redq[0][tid] + redq[1][tid] + redq[2][tid] + redq[3][tid];
    } else if (tid < 64) {
        int j = tid & 31;
        pssk[((size_t)bh * 8 + chunk) * 32 + j] =
            redk[0][j] + redk[1][j] + redk[2][j] + redk[3][j];
    }
}

// ---------------------------------------------------------------------------
// reduce partials -> normalize -> softmax -> M = Wproj_h @ attn
// ---------------------------------------------------------------------------
__global__ __launch_bounds__(256) void softproj_kernel(
    const float* __restrict__ pgram, const float* __restrict__ pssq,
    const float* __restrict__ pssk, const float* __restrict__ Wproj,
    const float* __restrict__ temp, float* __restrict__ Mm)
{
    __shared__ float att[32][33];
    __shared__ float nq[32], nk[32];

    const int bh = blockIdx.x;
    const int h = bh & 7;
    const int b = bh >> 3;
    const int tid = threadIdx.x;

    for (int p = tid; p < 1024; p += 256) {
        float s = 0.f;
        #pragma unroll
        for (int c = 0; c < 8; ++c) s += pgram[((size_t)bh * 8 + c) * 1024 + p];
        att[p >> 5][p & 31] = s;
    }
    if (tid < 32) {
        float s = 0.f;
        #pragma unroll
        for (int c = 0; c < 8; ++c) s += pssq[((size_t)bh * 8 + c) * 32 + tid];
        nq[tid] = fmaxf(sqrtf(s), 1e-12f);
    } else if (tid < 64) {
        int i = tid & 31;
        float s = 0.f;
        #pragma unroll
        for (int c = 0; c < 8; ++c) s += pssk[((size_t)bh * 8 + c) * 32 + i];
        nk[i] = fmaxf(sqrtf(s), 1e-12f);
    }
    __syncthreads();

    const float T = temp[h];
    if (tid < 32) {
        int i = tid;
        float row[32];
        float mx = -1e30f;
        float qi = T / nq[i];
        #pragma unroll
        for (int j = 0; j < 32; ++j) {
            float v = att[i][j] * qi / nk[j];
            row[j] = v;
            mx = fmaxf(mx, v);
        }
        float s = 0.f;
        #pragma unroll
        for (int j = 0; j < 32; ++j) { float e = expf(row[j] - mx); row[j] = e; s += e; }
        float inv = 1.f / s;
        #pragma unroll
        for (int j = 0; j < 32; ++j) att[i][j] = row[j] * inv;
    }
    __syncthreads();

    const int o = tid;
    float wp[32];
    #pragma unroll
    for (int i2 = 0; i2 < 32; i2 += 4)
        *(float4*)&wp[i2] = *(const float4*)&Wproj[(size_t)o * DIM_ + h * 32 + i2];
    float* mrow = Mm + ((size_t)b * DIM_ + o) * DIM_ + h * 32;
    #pragma unroll
    for (int j = 0; j < 32; ++j) {
        float s = 0.f;
        #pragma unroll
        for (int i = 0; i < 32; ++i) s = fmaf(wp[i], att[i][j], s);
        mrow[j] = s;
    }
}

// ---------------------------------------------------------------------------
// final: out[b][o][pix] = sum_{k<256} M[b][o][k] v[k][pix]
//                       + sum_{c<192} Wfus[o][c] xyz[c][pix]   (bf16 MFMA)
// ---------------------------------------------------------------------------
__global__ __launch_bounds__(256) void final_mfma_kernel(
    const float* __restrict__ Mm, const u16* __restrict__ vbuf,
    const float* __restrict__ xin, const float* __restrict__ yin,
    const float* __restrict__ zin, const float* __restrict__ Wfus,
    float* __restrict__ out)
{
    __shared__ u16 Alds[256 * 64];
    __shared__ u16 Blds[128 * 64];

    const int tid = threadIdx.x;
    const int b = blockIdx.y;
    const int px0 = blockIdx.x * 128;
    const int lane = tid & 63, wid = tid >> 6;
    const int g = lane >> 4, ln = lane & 15;
    const int m0 = wid * 64;
    f32x4 acc[4][8] = {};

    for (int kc = 0; kc < 7; ++kc) {
        {
            const int row = tid;
            const float* ap = (kc < 4)
                ? Mm + ((size_t)b * DIM_ + row) * DIM_ + kc * 64
                : Wfus + (size_t)row * 192 + (kc - 4) * 64;
            #pragma unroll
            for (int s = 0; s < 8; ++s) {
                float4 f0 = *(const float4*)(ap + s * 8);
                float4 f1 = *(const float4*)(ap + s * 8 + 4);
                uint4 pk;
                pk.x = f2bf(f0.x) | ((u32)f2bf(f0.y) << 16);
                pk.y = f2bf(f0.z) | ((u32)f2bf(f0.w) << 16);
                pk.z = f2bf(f1.x) | ((u32)f2bf(f1.y) << 16);
                pk.w = f2bf(f1.z) | ((u32)f2bf(f1.w) << 16);
                *(uint4*)&Alds[row * 64 + ((s * 8) ^ ((row & 7) << 3))] = pk;
            }
        }
        if (kc < 4) {
            const u16* vb = vbuf + ((size_t)b * DIM_ + kc * 64) * HW_ + px0;
            #pragma unroll
            for (int v4 = 0; v4 < 4; ++v4) {
                int it = tid + v4 * 256;
                int px = it & 127, cg = it >> 7;
                const u16* sp = vb + (size_t)(cg * 8) * HW_ + px;
                u32 wv[4];
                #pragma unroll
                for (int j = 0; j < 4; ++j)
                    wv[j] = (u32)sp[(size_t)(2 * j) * HW_] | ((u32)sp[(size_t)(2 * j + 1) * HW_] << 16);
                *(uint4*)&Blds[px * 64 + ((cg * 8) ^ ((px & 7) << 3))] =
                    make_uint4(wv[0], wv[1], wv[2], wv[3]);
            }
        } else {
            const float* src = (kc == 4) ? xin : (kc == 5) ? yin : zin;
            src += (size_t)b * CIN * HW_ + px0;
            #pragma unroll
            for (int v4 = 0; v4 < 4; ++v4) {
                int it = tid + v4 * 256;
                int px = it & 127, cg = it >> 7;
                const float* sp = src + (size_t)(cg * 8) * HW_ + px;
                u32 wv[4];
                #pragma unroll
                for (int j = 0; j < 4; ++j) {
                    float a = sp[(size_t)(2 * j) * HW_];
                    float c = sp[(size_t)(2 * j + 1) * HW_];
                    wv[j] = f2bf(a) | ((u32)f2bf(c) << 16);
                }
                *(uint4*)&Blds[px * 64 + ((cg * 8) ^ ((px & 7) << 3))] =
                    make_uint4(wv[0], wv[1], wv[2], wv[3]);
            }
        }
        __syncthreads();

        #pragma unroll
        for (int ks = 0; ks < 2; ++ks) {
            short8 af[4];
            #pragma unroll
            for (int fm = 0; fm < 4; ++fm) {
                int m = m0 + fm * 16 + ln;
                af[fm] = *(const short8*)&Alds[m * 64 + ((ks * 32 + g * 8) ^ ((m & 7) << 3))];
            }
            #pragma unroll
            for (int fn = 0; fn < 8; ++fn) {
                int p = fn * 16 + ln;
                short8 bf = *(const short8*)&Blds[p * 64 + ((ks * 32 + g * 8) ^ ((p & 7) << 3))];
                #pragma unroll
                for (int fm = 0; fm < 4; ++fm)
                    acc[fm][fn] = __builtin_amdgcn_mfma_f32_16x16x32_bf16(af[fm], bf, acc[fm][fn], 0, 0, 0);
            }
        }
        __syncthreads();
    }

    float* op = out + (size_t)b * DIM_ * HW_;
    #pragma unroll
    for (int fm = 0; fm < 4; ++fm)
        #pragma unroll
        for (int fn = 0; fn < 8; ++fn)
            #pragma unroll
            for (int r = 0; r < 4; ++r) {
                int ch = m0 + fm * 16 + g * 4 + r;
                op[(size_t)ch * HW_ + px0 + fn * 16 + ln] = acc[fm][fn][r];
            }
}

// ---------------------------------------------------------------------------
extern "C" void kernel_launch(void* const* d_in, const int* in_sizes, int n_in,
                              void* d_out, int out_size, void* d_ws, size_t ws_size,
                              hipStream_t stream) {
    (void)in_sizes; (void)n_in; (void)out_size; (void)ws_size;

    const float* x     = (const float*)d_in[0];
    const float* y     = (const float*)d_in[1];
    const float* z     = (const float*)d_in[2];
    const float* Wq    = (const float*)d_in[3];
    const float* Wqd   = (const float*)d_in[4];
    const float* Wk    = (const float*)d_in[5];
    const float* Wkd   = (const float*)d_in[6];
    const float* Wv    = (const float*)d_in[7];
    const float* Wvd   = (const float*)d_in[8];
    const float* Wproj = (const float*)d_in[9];
    const float* Wfus  = (const float*)d_in[10];
    const float* temp  = (const float*)d_in[11];

    const size_t QELEMS = (size_t)B_ * DIM_ * HW_;   // 33.5M elems, 64 MiB bf16

    u16* preb = (u16*)d_out;
    u16* qbuf = (u16*)d_out + QELEMS;
    u16* kvbuf = (u16*)d_ws;
    float* pgram = (float*)((char*)d_ws + QELEMS * sizeof(u16));
    float* pssq  = pgram + 64 * 8 * 1024;
    float* pssk  = pssq + 64 * 8 * 32;
    float* Mm    = pssk + 64 * 8 * 32;

    dim3 cgrid(128, B_);
    dim3 dgrid(4, DIM_, B_);

    conv_mfma_kernel<<<cgrid, 256, 0, stream>>>(x, Wq, preb);
    dw_kernel<<<dgrid, 256, 0, stream>>>(preb, Wqd, qbuf);
    conv_mfma_kernel<<<cgrid, 256, 0, stream>>>(y, Wk, preb);
    dw_kernel<<<dgrid, 256, 0, stream>>>(preb, Wkd, kvbuf);
    gram_mfma_kernel<<<dim3(8, 64), 256, 0, stream>>>(qbuf, kvbuf, pgram, pssq, pssk);
    softproj_kernel<<<64, 256, 0, stream>>>(pgram, pssq, pssk, Wproj, temp, Mm);
    conv_mfma_kernel<<<cgrid, 256, 0, stream>>>(z, Wv, preb);
    dw_kernel<<<dgrid, 256, 0, stream>>>(preb, Wvd, kvbuf);
    final_mfma_kernel<<<cgrid, 256, 0, stream>>>(Mm, kvbuf, x, y, z, Wfus, (float*)d_out);
}

// Round 4
// 319.824 us; speedup vs baseline: 3.9796x; 1.0087x over previous
//
#include <hip/hip_runtime.h>
#include <cstdint>

#define B_   8
#define CIN  64
#define DIM_ 256
#define H_   128
#define W_   128
#define HW_  (H_*W_)

typedef unsigned short u16;
typedef unsigned int   u32;
typedef short short8 __attribute__((ext_vector_type(8)));
typedef float f32x4  __attribute__((ext_vector_type(4)));

__device__ __forceinline__ u16 f2bf(float f) {
    u32 u = __float_as_uint(f);
    u32 r = (u + 0x7fffu + ((u >> 16) & 1u)) >> 16;
    return (u16)r;
}
__device__ __forceinline__ float bf2f(u16 h) {
    return __uint_as_float(((u32)h) << 16);
}

// ---------------------------------------------------------------------------
// conv1x1 as bf16 MFMA GEMM: pre[b][256][HW] = W[256x64] @ in[b][64][HW]
// ---------------------------------------------------------------------------
__global__ __launch_bounds__(256) void conv_mfma_kernel(
    const float* __restrict__ in, const float* __restrict__ Wc,
    u16* __restrict__ pre)
{
    __shared__ u16 Alds[256 * 64];
    __shared__ u16 Blds[128 * 64];

    const int tid = threadIdx.x;
    const int b = blockIdx.y;
    const int px0 = blockIdx.x * 128;

    {
        const int row = tid;
        const float* wp = Wc + (size_t)row * 64;
        #pragma unroll
        for (int s = 0; s < 8; ++s) {
            float4 f0 = *(const float4*)(wp + s * 8);
            float4 f1 = *(const float4*)(wp + s * 8 + 4);
            uint4 pk;
            pk.x = f2bf(f0.x) | ((u32)f2bf(f0.y) << 16);
            pk.y = f2bf(f0.z) | ((u32)f2bf(f0.w) << 16);
            pk.z = f2bf(f1.x) | ((u32)f2bf(f1.y) << 16);
            pk.w = f2bf(f1.z) | ((u32)f2bf(f1.w) << 16);
            *(uint4*)&Alds[row * 64 + ((s * 8) ^ ((row & 7) << 3))] = pk;
        }
    }
    #pragma unroll
    for (int v4 = 0; v4 < 4; ++v4) {
        int it = tid + v4 * 256;
        int px = it & 127, cg = it >> 7;
        const float* sp = in + ((size_t)b * CIN + cg * 8) * HW_ + px0 + px;
        u32 wv[4];
        #pragma unroll
        for (int j = 0; j < 4; ++j) {
            float a = sp[(size_t)(2 * j) * HW_];
            float c = sp[(size_t)(2 * j + 1) * HW_];
            wv[j] = f2bf(a) | ((u32)f2bf(c) << 16);
        }
        *(uint4*)&Blds[px * 64 + ((cg * 8) ^ ((px & 7) << 3))] =
            make_uint4(wv[0], wv[1], wv[2], wv[3]);
    }
    __syncthreads();

    const int lane = tid & 63, wid = tid >> 6;
    const int g = lane >> 4, ln = lane & 15;
    const int m0 = wid * 64;
    f32x4 acc[4][8] = {};

    #pragma unroll
    for (int ks = 0; ks < 2; ++ks) {
        short8 af[4];
        #pragma unroll
        for (int fm = 0; fm < 4; ++fm) {
            int m = m0 + fm * 16 + ln;
            af[fm] = *(const short8*)&Alds[m * 64 + ((ks * 32 + g * 8) ^ ((m & 7) << 3))];
        }
        #pragma unroll
        for (int fn = 0; fn < 8; ++fn) {
            int p = fn * 16 + ln;
            short8 bf = *(const short8*)&Blds[p * 64 + ((ks * 32 + g * 8) ^ ((p & 7) << 3))];
            #pragma unroll
            for (int fm = 0; fm < 4; ++fm)
                acc[fm][fn] = __builtin_amdgcn_mfma_f32_16x16x32_bf16(af[fm], bf, acc[fm][fn], 0, 0, 0);
        }
    }

    u16* op = pre + (size_t)b * DIM_ * HW_;
    #pragma unroll
    for (int fm = 0; fm < 4; ++fm)
        #pragma unroll
        for (int fn = 0; fn < 8; ++fn)
            #pragma unroll
            for (int r = 0; r < 4; ++r) {
                int ch = m0 + fm * 16 + g * 4 + r;
                op[(size_t)ch * HW_ + px0 + fn * 16 + ln] = f2bf(acc[fm][fn][r]);
            }
}

// ---------------------------------------------------------------------------
// depthwise 3x3 bf16 -> bf16, SAME padding. grid (4 row-strips, 256 ch, 8 b)
// ---------------------------------------------------------------------------
__global__ __launch_bounds__(256) void dw_kernel(
    const u16* __restrict__ pre, const float* __restrict__ Wd,
    u16* __restrict__ dst)
{
    __shared__ u16 t0[34][144];

    const int tid = threadIdx.x;
    const int y0 = blockIdx.x * 32;
    const int ch = blockIdx.y;
    const int b = blockIdx.z;
    const u16* src = pre + ((size_t)b * DIM_ + ch) * HW_;

    for (int i = tid; i < 68; i += 256)
        t0[i >> 1][(i & 1) ? 136 : 7] = 0;
    for (int i = tid; i < 544; i += 256) {
        int row = i >> 4, seg = i & 15;
        int gy = y0 - 1 + row;
        uint4 v = make_uint4(0, 0, 0, 0);
        if (gy >= 0 && gy < H_) v = *(const uint4*)(src + (size_t)gy * W_ + seg * 8);
        *(uint4*)&t0[row][8 + seg * 8] = v;
    }
    const float* wv = Wd + (size_t)ch * 9;
    float w00 = wv[0], w01 = wv[1], w02 = wv[2];
    float w10 = wv[3], w11 = wv[4], w12 = wv[5];
    float w20 = wv[6], w21 = wv[7], w22 = wv[8];
    __syncthreads();

    const int px = tid & 127, half = tid >> 7;
    u16* op = dst + ((size_t)b * DIM_ + ch) * HW_;
    float h0m2 = 0.f, h0m1 = 0.f, h1m1 = 0.f;
    #pragma unroll
    for (int y = 0; y < 18; ++y) {
        int r = half * 16 + y;
        float v0 = bf2f(t0[r][7 + px]);
        float v1 = bf2f(t0[r][8 + px]);
        float v2 = bf2f(t0[r][9 + px]);
        float h0 = fmaf(v0, w00, fmaf(v1, w01, v2 * w02));
        float h1 = fmaf(v0, w10, fmaf(v1, w11, v2 * w12));
        float h2 = fmaf(v0, w20, fmaf(v1, w21, v2 * w22));
        if (y >= 2)
            op[(size_t)(y0 + half * 16 + y - 2) * W_ + px] = f2bf(h0m2 + h1m1 + h2);
        h0m2 = h0m1; h0m1 = h0; h1m1 = h1;
    }
}

// ---------------------------------------------------------------------------
// Gram via MFMA (verified in R3): direct global fragments, sumsq = diagonals
// ---------------------------------------------------------------------------
__global__ __launch_bounds__(256) void gram_mfma_kernel(
    const u16* __restrict__ q, const u16* __restrict__ k,
    float* __restrict__ pgram, float* __restrict__ pssq, float* __restrict__ pssk)
{
    __shared__ float red[4][1024];
    __shared__ float redq[4][32];
    __shared__ float redk[4][32];

    const int bh = blockIdx.y;
    const int chunk = blockIdx.x;
    const int tid = threadIdx.x;
    const int lane = tid & 63, wid = tid >> 6;
    const int g = lane >> 4, ln = lane & 15;

    const size_t off = (size_t)(bh * 32 + ln) * HW_ + chunk * 2048 + wid * 512 + g * 8;
    const u16* qp = q + off;
    const u16* kp = k + off;

    f32x4 aqk[2][2] = {};
    f32x4 aqq[2] = {};
    f32x4 akk[2] = {};

    #pragma unroll 4
    for (int n = 0; n < 512; n += 32) {
        short8 qf[2], kf[2];
        qf[0] = *(const short8*)(qp + n);
        qf[1] = *(const short8*)(qp + (size_t)16 * HW_ + n);
        kf[0] = *(const short8*)(kp + n);
        kf[1] = *(const short8*)(kp + (size_t)16 * HW_ + n);
        #pragma unroll
        for (int ti = 0; ti < 2; ++ti)
            #pragma unroll
            for (int tj = 0; tj < 2; ++tj)
                aqk[ti][tj] = __builtin_amdgcn_mfma_f32_16x16x32_bf16(qf[ti], kf[tj], aqk[ti][tj], 0, 0, 0);
        #pragma unroll
        for (int ti = 0; ti < 2; ++ti) {
            aqq[ti] = __builtin_amdgcn_mfma_f32_16x16x32_bf16(qf[ti], qf[ti], aqq[ti], 0, 0, 0);
            akk[ti] = __builtin_amdgcn_mfma_f32_16x16x32_bf16(kf[ti], kf[ti], akk[ti], 0, 0, 0);
        }
    }

    #pragma unroll
    for (int ti = 0; ti < 2; ++ti)
        #pragma unroll
        for (int tj = 0; tj < 2; ++tj)
            #pragma unroll
            for (int r = 0; r < 4; ++r)
                red[wid][(ti * 16 + g * 4 + r) * 32 + tj * 16 + ln] = aqk[ti][tj][r];
    if ((ln >> 2) == g) {
        #pragma unroll
        for (int ti = 0; ti < 2; ++ti) {
            redq[wid][ti * 16 + ln] = aqq[ti][ln & 3];
            redk[wid][ti * 16 + ln] = akk[ti][ln & 3];
        }
    }
    __syncthreads();

    for (int p = tid; p < 1024; p += 256) {
        float s = red[0][p] + red[1][p] + red[2][p] + red[3][p];
        pgram[((size_t)bh * 8 + chunk) * 1024 + p] = s;
    }
    if (tid < 32) {
        pssq[((size_t)bh * 8 + chunk) * 32 + tid] =
            redq[0][tid] + redq[1][tid] + redq[2][tid] + redq[3][tid];
    } else if (tid < 64) {
        int j = tid & 31;
        pssk[((size_t)bh * 8 + chunk) * 32 + j] =
            redk[0][j] + redk[1][j] + redk[2][j] + redk[3][j];
    }
}

// ---------------------------------------------------------------------------
// reduce partials -> normalize -> softmax -> Amm(bf16) = Wproj_h @ attn
// ---------------------------------------------------------------------------
__global__ __launch_bounds__(256) void softproj_kernel(
    const float* __restrict__ pgram, const float* __restrict__ pssq,
    const float* __restrict__ pssk, const float* __restrict__ Wproj,
    const float* __restrict__ temp, u16* __restrict__ Amm)
{
    __shared__ float att[32][33];
    __shared__ float nq[32], nk[32];

    const int bh = blockIdx.x;
    const int h = bh & 7;
    const int b = bh >> 3;
    const int tid = threadIdx.x;

    for (int p = tid; p < 1024; p += 256) {
        float s = 0.f;
        #pragma unroll
        for (int c = 0; c < 8; ++c) s += pgram[((size_t)bh * 8 + c) * 1024 + p];
        att[p >> 5][p & 31] = s;
    }
    if (tid < 32) {
        float s = 0.f;
        #pragma unroll
        for (int c = 0; c < 8; ++c) s += pssq[((size_t)bh * 8 + c) * 32 + tid];
        nq[tid] = fmaxf(sqrtf(s), 1e-12f);
    } else if (tid < 64) {
        int i = tid & 31;
        float s = 0.f;
        #pragma unroll
        for (int c = 0; c < 8; ++c) s += pssk[((size_t)bh * 8 + c) * 32 + i];
        nk[i] = fmaxf(sqrtf(s), 1e-12f);
    }
    __syncthreads();

    const float T = temp[h];
    if (tid < 32) {
        int i = tid;
        float row[32];
        float mx = -1e30f;
        float qi = T / nq[i];
        #pragma unroll
        for (int j = 0; j < 32; ++j) {
            float v = att[i][j] * qi / nk[j];
            row[j] = v;
            mx = fmaxf(mx, v);
        }
        float s = 0.f;
        #pragma unroll
        for (int j = 0; j < 32; ++j) { float e = expf(row[j] - mx); row[j] = e; s += e; }
        float inv = 1.f / s;
        #pragma unroll
        for (int j = 0; j < 32; ++j) att[i][j] = row[j] * inv;
    }
    __syncthreads();

    const int o = tid;
    float wp[32];
    #pragma unroll
    for (int i2 = 0; i2 < 32; i2 += 4)
        *(float4*)&wp[i2] = *(const float4*)&Wproj[(size_t)o * DIM_ + h * 32 + i2];
    u16* arow = Amm + ((size_t)b * DIM_ + o) * DIM_ + h * 32;
    #pragma unroll
    for (int j = 0; j < 32; ++j) {
        float s = 0.f;
        #pragma unroll
        for (int i = 0; i < 32; ++i) s = fmaf(wp[i], att[i][j], s);
        arow[j] = f2bf(s);
    }
}

// ---------------------------------------------------------------------------
// cast Wfus [256][192] fp32 -> bf16 (once)
// ---------------------------------------------------------------------------
__global__ __launch_bounds__(256) void wfus_cast_kernel(
    const float* __restrict__ Wfus, u16* __restrict__ Afus)
{
    int idx = blockIdx.x * 256 + threadIdx.x;   // 24 blocks * 256 thr * 8 el = 49152
    int base = idx * 8;
    float4 f0 = *(const float4*)(Wfus + base);
    float4 f1 = *(const float4*)(Wfus + base + 4);
    uint4 pk;
    pk.x = f2bf(f0.x) | ((u32)f2bf(f0.y) << 16);
    pk.y = f2bf(f0.z) | ((u32)f2bf(f0.w) << 16);
    pk.z = f2bf(f1.x) | ((u32)f2bf(f1.y) << 16);
    pk.w = f2bf(f1.z) | ((u32)f2bf(f1.w) << 16);
    *(uint4*)(Afus + base) = pk;
}

// ---------------------------------------------------------------------------
// final2: out[b][o][px] = A[b][o][0:256] @ v  +  A2[o][0:192] @ xyz
// A from precast bf16 global (direct fragments, L2-hot); B via wide loads ->
// swizzled LDS transpose; double-buffered, 1 barrier / K-chunk, issue-early.
// grid (128 px-panels, 8 b), 256 thr (4 waves, each 64out x 128px)
// ---------------------------------------------------------------------------
__global__ __launch_bounds__(256, 2) void final2_kernel(
    const u16* __restrict__ Amm, const u16* __restrict__ Afus,
    const u16* __restrict__ vbuf,
    const float* __restrict__ xin, const float* __restrict__ yin,
    const float* __restrict__ zin, float* __restrict__ out)
{
    __shared__ u16 Bl[2][128 * 64];

    const int tid = threadIdx.x;
    const int b = blockIdx.y;
    const int px0 = blockIdx.x * 128;
    const int lane = tid & 63, wid = tid >> 6;
    const int g = lane >> 4, ln = lane & 15;
    const int m0 = wid * 64;

    f32x4 acc[4][8] = {};
    uint4  gq[2][4];
    float4 gx[2][8];
    short8 af[2][8];

    auto loadB = [&](int kc, uint4* q4, float4* x4) {
        if (kc < 4) {
            #pragma unroll
            for (int i = 0; i < 4; ++i) {
                int tt = i * 256 + tid;
                int r = tt >> 4, pc = tt & 15;
                q4[i] = *(const uint4*)(vbuf + ((size_t)b * DIM_ + kc * 64 + r) * HW_ + px0 + pc * 8);
            }
        } else {
            #pragma unroll
            for (int i = 0; i < 4; ++i) {
                int tt = i * 256 + tid;
                int r = tt >> 4, pc = tt & 15;
                int c = kc * 64 + r - 256;
                const float* basep = (c < 64) ? xin : (c < 128) ? yin : zin;
                const float* sp = basep + ((size_t)b * CIN + (c & 63)) * HW_ + px0 + pc * 8;
                x4[2 * i]     = *(const float4*)sp;
                x4[2 * i + 1] = *(const float4*)(sp + 4);
            }
        }
    };
    auto writeB = [&](int kc, int buf, uint4* q4, float4* x4) {
        u16* dst = &Bl[buf][0];
        #pragma unroll
        for (int i = 0; i < 4; ++i) {
            int tt = i * 256 + tid;
            int r = tt >> 4, pc = tt & 15;
            if (kc < 4) {
                #pragma unroll
                for (int e = 0; e < 4; ++e) {
                    u32 w = ((const u32*)&q4[i])[e];
                    int j0 = 2 * e, j1 = 2 * e + 1;
                    dst[(pc * 8 + j0) * 64 + (((r >> 3) ^ j0) << 3) + (r & 7)] = (u16)w;
                    dst[(pc * 8 + j1) * 64 + (((r >> 3) ^ j1) << 3) + (r & 7)] = (u16)(w >> 16);
                }
            } else {
                float f[8];
                *(float4*)&f[0] = x4[2 * i];
                *(float4*)&f[4] = x4[2 * i + 1];
                #pragma unroll
                for (int j = 0; j < 8; ++j)
                    dst[(pc * 8 + j) * 64 + (((r >> 3) ^ j) << 3) + (r & 7)] = f2bf(f[j]);
            }
        }
    };
    auto loadA = [&](int kc, short8* a8) {
        #pragma unroll
        for (int ks = 0; ks < 2; ++ks)
            #pragma unroll
            for (int fm = 0; fm < 4; ++fm) {
                int m = m0 + fm * 16 + ln;
                const u16* p = (kc < 4)
                    ? Amm + ((size_t)b * DIM_ + m) * DIM_ + kc * 64 + ks * 32 + g * 8
                    : Afus + (size_t)m * 192 + (kc - 4) * 64 + ks * 32 + g * 8;
                a8[ks * 4 + fm] = *(const short8*)p;
            }
    };

    // prologue: stage kc=0
    loadB(0, gq[0], gx[0]);
    loadA(0, af[0]);
    writeB(0, 0, gq[0], gx[0]);
    __syncthreads();

    #pragma unroll
    for (int kc = 0; kc < 7; ++kc) {
        const int cur = kc & 1, nxt = cur ^ 1;
        if (kc < 6) {                       // issue next-chunk globals early
            loadB(kc + 1, gq[nxt], gx[nxt]);
            loadA(kc + 1, af[nxt]);
        }
        // MFMA current chunk
        #pragma unroll
        for (int ks = 0; ks < 2; ++ks) {
            #pragma unroll
            for (int fn = 0; fn < 8; ++fn) {
                int p = fn * 16 + ln;
                short8 bf = *(const short8*)&Bl[cur][p * 64 + ((ks * 32 + g * 8) ^ ((p & 7) << 3))];
                #pragma unroll
                for (int fm = 0; fm < 4; ++fm)
                    acc[fm][fn] = __builtin_amdgcn_mfma_f32_16x16x32_bf16(af[cur][ks * 4 + fm], bf, acc[fm][fn], 0, 0, 0);
            }
        }
        if (kc < 6) {
            writeB(kc + 1, nxt, gq[nxt], gx[nxt]);
            __syncthreads();
        }
    }

    float* op = out + (size_t)b * DIM_ * HW_;
    #pragma unroll
    for (int fm = 0; fm < 4; ++fm)
        #pragma unroll
        for (int fn = 0; fn < 8; ++fn)
            #pragma unroll
            for (int r = 0; r < 4; ++r) {
                int ch = m0 + fm * 16 + g * 4 + r;
                op[(size_t)ch * HW_ + px0 + fn * 16 + ln] = acc[fm][fn][r];
            }
}

// ---------------------------------------------------------------------------
extern "C" void kernel_launch(void* const* d_in, const int* in_sizes, int n_in,
                              void* d_out, int out_size, void* d_ws, size_t ws_size,
                              hipStream_t stream) {
    (void)in_sizes; (void)n_in; (void)out_size; (void)ws_size;

    const float* x     = (const float*)d_in[0];
    const float* y     = (const float*)d_in[1];
    const float* z     = (const float*)d_in[2];
    const float* Wq    = (const float*)d_in[3];
    const float* Wqd   = (const float*)d_in[4];
    const float* Wk    = (const float*)d_in[5];
    const float* Wkd   = (const float*)d_in[6];
    const float* Wv    = (const float*)d_in[7];
    const float* Wvd   = (const float*)d_in[8];
    const float* Wproj = (const float*)d_in[9];
    const float* Wfus  = (const float*)d_in[10];
    const float* temp  = (const float*)d_in[11];

    const size_t QELEMS = (size_t)B_ * DIM_ * HW_;   // 33.5M elems, 64 MiB bf16

    u16* preb = (u16*)d_out;                  // dead after dw
    u16* qbuf = (u16*)d_out + QELEMS;         // dead after gram
    u16* kvbuf = (u16*)d_ws;                  // k, then v
    char* wsp = (char*)d_ws + QELEMS * sizeof(u16);
    float* pgram = (float*)wsp;                       wsp += 64 * 8 * 1024 * 4;
    float* pssq  = (float*)wsp;                       wsp += 64 * 8 * 32 * 4;
    float* pssk  = (float*)wsp;                       wsp += 64 * 8 * 32 * 4;
    u16*   Amm   = (u16*)wsp;                         wsp += (size_t)B_ * DIM_ * DIM_ * 2;
    u16*   Afus  = (u16*)wsp;

    dim3 cgrid(128, B_);
    dim3 dgrid(4, DIM_, B_);

    wfus_cast_kernel<<<24, 256, 0, stream>>>(Wfus, Afus);
    conv_mfma_kernel<<<cgrid, 256, 0, stream>>>(x, Wq, preb);
    dw_kernel<<<dgrid, 256, 0, stream>>>(preb, Wqd, qbuf);
    conv_mfma_kernel<<<cgrid, 256, 0, stream>>>(y, Wk, preb);
    dw_kernel<<<dgrid, 256, 0, stream>>>(preb, Wkd, kvbuf);
    gram_mfma_kernel<<<dim3(8, 64), 256, 0, stream>>>(qbuf, kvbuf, pgram, pssq, pssk);
    softproj_kernel<<<64, 256, 0, stream>>>(pgram, pssq, pssk, Wproj, temp, Amm);
    conv_mfma_kernel<<<cgrid, 256, 0, stream>>>(z, Wv, preb);
    dw_kernel<<<dgrid, 256, 0, stream>>>(preb, Wvd, kvbuf);
    final2_kernel<<<cgrid, 256, 0, stream>>>(Amm, Afus, kvbuf, x, y, z, (float*)d_out);
}

// Round 5
// 286.307 us; speedup vs baseline: 4.4454x; 1.1171x over previous
//
#include <hip/hip_runtime.h>
#include <cstdint>

#define B_   8
#define CIN  64
#define DIM_ 256
#define H_   128
#define W_   128
#define HW_  (H_*W_)

typedef unsigned short u16;
typedef unsigned int   u32;
typedef short short8 __attribute__((ext_vector_type(8)));
typedef float f32x4  __attribute__((ext_vector_type(4)));

__device__ __forceinline__ u16 f2bf(float f) {
    u32 u = __float_as_uint(f);
    u32 r = (u + 0x7fffu + ((u >> 16) & 1u)) >> 16;
    return (u16)r;
}
__device__ __forceinline__ float bf2f(u16 h) {
    return __uint_as_float(((u32)h) << 16);
}

// ---------------------------------------------------------------------------
// conv1x1 as bf16 MFMA GEMM: pre[b][256][HW] = W[256x64] @ in[b][64][HW]
// ---------------------------------------------------------------------------
__global__ __launch_bounds__(256) void conv_mfma_kernel(
    const float* __restrict__ in, const float* __restrict__ Wc,
    u16* __restrict__ pre)
{
    __shared__ u16 Alds[256 * 64];
    __shared__ u16 Blds[128 * 64];

    const int tid = threadIdx.x;
    const int b = blockIdx.y;
    const int px0 = blockIdx.x * 128;

    {
        const int row = tid;
        const float* wp = Wc + (size_t)row * 64;
        #pragma unroll
        for (int s = 0; s < 8; ++s) {
            float4 f0 = *(const float4*)(wp + s * 8);
            float4 f1 = *(const float4*)(wp + s * 8 + 4);
            uint4 pk;
            pk.x = f2bf(f0.x) | ((u32)f2bf(f0.y) << 16);
            pk.y = f2bf(f0.z) | ((u32)f2bf(f0.w) << 16);
            pk.z = f2bf(f1.x) | ((u32)f2bf(f1.y) << 16);
            pk.w = f2bf(f1.z) | ((u32)f2bf(f1.w) << 16);
            *(uint4*)&Alds[row * 64 + ((s * 8) ^ ((row & 7) << 3))] = pk;
        }
    }
    #pragma unroll
    for (int v4 = 0; v4 < 4; ++v4) {
        int it = tid + v4 * 256;
        int px = it & 127, cg = it >> 7;
        const float* sp = in + ((size_t)b * CIN + cg * 8) * HW_ + px0 + px;
        u32 wv[4];
        #pragma unroll
        for (int j = 0; j < 4; ++j) {
            float a = sp[(size_t)(2 * j) * HW_];
            float c = sp[(size_t)(2 * j + 1) * HW_];
            wv[j] = f2bf(a) | ((u32)f2bf(c) << 16);
        }
        *(uint4*)&Blds[px * 64 + ((cg * 8) ^ ((px & 7) << 3))] =
            make_uint4(wv[0], wv[1], wv[2], wv[3]);
    }
    __syncthreads();

    const int lane = tid & 63, wid = tid >> 6;
    const int g = lane >> 4, ln = lane & 15;
    const int m0 = wid * 64;
    f32x4 acc[4][8] = {};

    #pragma unroll
    for (int ks = 0; ks < 2; ++ks) {
        short8 af[4];
        #pragma unroll
        for (int fm = 0; fm < 4; ++fm) {
            int m = m0 + fm * 16 + ln;
            af[fm] = *(const short8*)&Alds[m * 64 + ((ks * 32 + g * 8) ^ ((m & 7) << 3))];
        }
        #pragma unroll
        for (int fn = 0; fn < 8; ++fn) {
            int p = fn * 16 + ln;
            short8 bf = *(const short8*)&Blds[p * 64 + ((ks * 32 + g * 8) ^ ((p & 7) << 3))];
            #pragma unroll
            for (int fm = 0; fm < 4; ++fm)
                acc[fm][fn] = __builtin_amdgcn_mfma_f32_16x16x32_bf16(af[fm], bf, acc[fm][fn], 0, 0, 0);
        }
    }

    u16* op = pre + (size_t)b * DIM_ * HW_;
    #pragma unroll
    for (int fm = 0; fm < 4; ++fm)
        #pragma unroll
        for (int fn = 0; fn < 8; ++fn)
            #pragma unroll
            for (int r = 0; r < 4; ++r) {
                int ch = m0 + fm * 16 + g * 4 + r;
                op[(size_t)ch * HW_ + px0 + fn * 16 + ln] = f2bf(acc[fm][fn][r]);
            }
}

// ---------------------------------------------------------------------------
// depthwise 3x3 bf16 -> bf16, SAME padding. grid (4 row-strips, 256 ch, 8 b)
// ---------------------------------------------------------------------------
__global__ __launch_bounds__(256) void dw_kernel(
    const u16* __restrict__ pre, const float* __restrict__ Wd,
    u16* __restrict__ dst)
{
    __shared__ u16 t0[34][144];

    const int tid = threadIdx.x;
    const int y0 = blockIdx.x * 32;
    const int ch = blockIdx.y;
    const int b = blockIdx.z;
    const u16* src = pre + ((size_t)b * DIM_ + ch) * HW_;

    for (int i = tid; i < 68; i += 256)
        t0[i >> 1][(i & 1) ? 136 : 7] = 0;
    for (int i = tid; i < 544; i += 256) {
        int row = i >> 4, seg = i & 15;
        int gy = y0 - 1 + row;
        uint4 v = make_uint4(0, 0, 0, 0);
        if (gy >= 0 && gy < H_) v = *(const uint4*)(src + (size_t)gy * W_ + seg * 8);
        *(uint4*)&t0[row][8 + seg * 8] = v;
    }
    const float* wv = Wd + (size_t)ch * 9;
    float w00 = wv[0], w01 = wv[1], w02 = wv[2];
    float w10 = wv[3], w11 = wv[4], w12 = wv[5];
    float w20 = wv[6], w21 = wv[7], w22 = wv[8];
    __syncthreads();

    const int px = tid & 127, half = tid >> 7;
    u16* op = dst + ((size_t)b * DIM_ + ch) * HW_;
    float h0m2 = 0.f, h0m1 = 0.f, h1m1 = 0.f;
    #pragma unroll
    for (int y = 0; y < 18; ++y) {
        int r = half * 16 + y;
        float v0 = bf2f(t0[r][7 + px]);
        float v1 = bf2f(t0[r][8 + px]);
        float v2 = bf2f(t0[r][9 + px]);
        float h0 = fmaf(v0, w00, fmaf(v1, w01, v2 * w02));
        float h1 = fmaf(v0, w10, fmaf(v1, w11, v2 * w12));
        float h2 = fmaf(v0, w20, fmaf(v1, w21, v2 * w22));
        if (y >= 2)
            op[(size_t)(y0 + half * 16 + y - 2) * W_ + px] = f2bf(h0m2 + h1m1 + h2);
        h0m2 = h0m1; h0m1 = h0; h1m1 = h1;
    }
}

// ---------------------------------------------------------------------------
// Gram via MFMA (verified): direct global fragments, sumsq = diagonals
// ---------------------------------------------------------------------------
__global__ __launch_bounds__(256) void gram_mfma_kernel(
    const u16* __restrict__ q, const u16* __restrict__ k,
    float* __restrict__ pgram, float* __restrict__ pssq, float* __restrict__ pssk)
{
    __shared__ float red[4][1024];
    __shared__ float redq[4][32];
    __shared__ float redk[4][32];

    const int bh = blockIdx.y;
    const int chunk = blockIdx.x;
    const int tid = threadIdx.x;
    const int lane = tid & 63, wid = tid >> 6;
    const int g = lane >> 4, ln = lane & 15;

    const size_t off = (size_t)(bh * 32 + ln) * HW_ + chunk * 2048 + wid * 512 + g * 8;
    const u16* qp = q + off;
    const u16* kp = k + off;

    f32x4 aqk[2][2] = {};
    f32x4 aqq[2] = {};
    f32x4 akk[2] = {};

    #pragma unroll 4
    for (int n = 0; n < 512; n += 32) {
        short8 qf[2], kf[2];
        qf[0] = *(const short8*)(qp + n);
        qf[1] = *(const short8*)(qp + (size_t)16 * HW_ + n);
        kf[0] = *(const short8*)(kp + n);
        kf[1] = *(const short8*)(kp + (size_t)16 * HW_ + n);
        #pragma unroll
        for (int ti = 0; ti < 2; ++ti)
            #pragma unroll
            for (int tj = 0; tj < 2; ++tj)
                aqk[ti][tj] = __builtin_amdgcn_mfma_f32_16x16x32_bf16(qf[ti], kf[tj], aqk[ti][tj], 0, 0, 0);
        #pragma unroll
        for (int ti = 0; ti < 2; ++ti) {
            aqq[ti] = __builtin_amdgcn_mfma_f32_16x16x32_bf16(qf[ti], qf[ti], aqq[ti], 0, 0, 0);
            akk[ti] = __builtin_amdgcn_mfma_f32_16x16x32_bf16(kf[ti], kf[ti], akk[ti], 0, 0, 0);
        }
    }

    #pragma unroll
    for (int ti = 0; ti < 2; ++ti)
        #pragma unroll
        for (int tj = 0; tj < 2; ++tj)
            #pragma unroll
            for (int r = 0; r < 4; ++r)
                red[wid][(ti * 16 + g * 4 + r) * 32 + tj * 16 + ln] = aqk[ti][tj][r];
    if ((ln >> 2) == g) {
        #pragma unroll
        for (int ti = 0; ti < 2; ++ti) {
            redq[wid][ti * 16 + ln] = aqq[ti][ln & 3];
            redk[wid][ti * 16 + ln] = akk[ti][ln & 3];
        }
    }
    __syncthreads();

    for (int p = tid; p < 1024; p += 256) {
        float s = red[0][p] + red[1][p] + red[2][p] + red[3][p];
        pgram[((size_t)bh * 8 + chunk) * 1024 + p] = s;
    }
    if (tid < 32) {
        pssq[((size_t)bh * 8 + chunk) * 32 + tid] =
            redq[0][tid] + redq[1][tid] + redq[2][tid] + redq[3][tid];
    } else if (tid < 64) {
        int j = tid & 31;
        pssk[((size_t)bh * 8 + chunk) * 32 + j] =
            redk[0][j] + redk[1][j] + redk[2][j] + redk[3][j];
    }
}

// ---------------------------------------------------------------------------
// reduce partials -> normalize -> softmax -> Amm(bf16) = Wproj_h @ attn
// ---------------------------------------------------------------------------
__global__ __launch_bounds__(256) void softproj_kernel(
    const float* __restrict__ pgram, const float* __restrict__ pssq,
    const float* __restrict__ pssk, const float* __restrict__ Wproj,
    const float* __restrict__ temp, u16* __restrict__ Amm)
{
    __shared__ float att[32][33];
    __shared__ float nq[32], nk[32];

    const int bh = blockIdx.x;
    const int h = bh & 7;
    const int b = bh >> 3;
    const int tid = threadIdx.x;

    for (int p = tid; p < 1024; p += 256) {
        float s = 0.f;
        #pragma unroll
        for (int c = 0; c < 8; ++c) s += pgram[((size_t)bh * 8 + c) * 1024 + p];
        att[p >> 5][p & 31] = s;
    }
    if (tid < 32) {
        float s = 0.f;
        #pragma unroll
        for (int c = 0; c < 8; ++c) s += pssq[((size_t)bh * 8 + c) * 32 + tid];
        nq[tid] = fmaxf(sqrtf(s), 1e-12f);
    } else if (tid < 64) {
        int i = tid & 31;
        float s = 0.f;
        #pragma unroll
        for (int c = 0; c < 8; ++c) s += pssk[((size_t)bh * 8 + c) * 32 + i];
        nk[i] = fmaxf(sqrtf(s), 1e-12f);
    }
    __syncthreads();

    const float T = temp[h];
    if (tid < 32) {
        int i = tid;
        float row[32];
        float mx = -1e30f;
        float qi = T / nq[i];
        #pragma unroll
        for (int j = 0; j < 32; ++j) {
            float v = att[i][j] * qi / nk[j];
            row[j] = v;
            mx = fmaxf(mx, v);
        }
        float s = 0.f;
        #pragma unroll
        for (int j = 0; j < 32; ++j) { float e = expf(row[j] - mx); row[j] = e; s += e; }
        float inv = 1.f / s;
        #pragma unroll
        for (int j = 0; j < 32; ++j) att[i][j] = row[j] * inv;
    }
    __syncthreads();

    const int o = tid;
    float wp[32];
    #pragma unroll
    for (int i2 = 0; i2 < 32; i2 += 4)
        *(float4*)&wp[i2] = *(const float4*)&Wproj[(size_t)o * DIM_ + h * 32 + i2];
    u16* arow = Amm + ((size_t)b * DIM_ + o) * DIM_ + h * 32;
    #pragma unroll
    for (int j = 0; j < 32; ++j) {
        float s = 0.f;
        #pragma unroll
        for (int i = 0; i < 32; ++i) s = fmaf(wp[i], att[i][j], s);
        arow[j] = f2bf(s);
    }
}

// ---------------------------------------------------------------------------
// cast Wfus [256][192] fp32 -> bf16 (once)
// ---------------------------------------------------------------------------
__global__ __launch_bounds__(256) void wfus_cast_kernel(
    const float* __restrict__ Wfus, u16* __restrict__ Afus)
{
    int idx = blockIdx.x * 256 + threadIdx.x;
    int base = idx * 8;
    float4 f0 = *(const float4*)(Wfus + base);
    float4 f1 = *(const float4*)(Wfus + base + 4);
    uint4 pk;
    pk.x = f2bf(f0.x) | ((u32)f2bf(f0.y) << 16);
    pk.y = f2bf(f0.z) | ((u32)f2bf(f0.w) << 16);
    pk.z = f2bf(f1.x) | ((u32)f2bf(f1.y) << 16);
    pk.w = f2bf(f1.z) | ((u32)f2bf(f1.w) << 16);
    *(uint4*)(Afus + base) = pk;
}

// ---------------------------------------------------------------------------
// final3: out[b][o][px] = A[b][o][0:256] @ v + A2[o][0:192] @ xyz
// 4 waves x (32out x 128px); A direct-from-global bf16; B double-buffered LDS
// (conflict-free swizzled [px][64], uint4 writes), 1 barrier/chunk, T14
// issue-early loads into named constant-indexed regs (no pointer lambdas).
// grid (128 px-panels, 2 o-groups, 8 b)
// ---------------------------------------------------------------------------
#define LOADB_F3(KC, W) do {                                                    \
    if ((KC) < 4) {                                                             \
        _Pragma("unroll") for (int i_ = 0; i_ < 2; ++i_) {                      \
            const u16* vb_ = vbuf + ((size_t)b * DIM_ + (KC) * 64 + (qq0 + 2 * i_) * 16) * HW_ + px0 + pxu; \
            _Pragma("unroll") for (int jj_ = 0; jj_ < 8; ++jj_)                 \
                W[i_][jj_] = (u32)vb_[(size_t)(2 * jj_) * HW_]                  \
                           | ((u32)vb_[(size_t)(2 * jj_ + 1) * HW_] << 16);     \
        }                                                                       \
    } else {                                                                    \
        const float* bp_ = ((KC) == 4) ? xin : ((KC) == 5) ? yin : zin;         \
        _Pragma("unroll") for (int i_ = 0; i_ < 2; ++i_) {                      \
            const float* sp_ = bp_ + ((size_t)b * CIN + (qq0 + 2 * i_) * 16) * HW_ + px0 + pxu; \
            _Pragma("unroll") for (int jj_ = 0; jj_ < 8; ++jj_)                 \
                W[i_][jj_] = (u32)f2bf(sp_[(size_t)(2 * jj_) * HW_])            \
                           | ((u32)f2bf(sp_[(size_t)(2 * jj_ + 1) * HW_]) << 16); \
        }                                                                       \
    } } while (0)

#define WRITEB_F3(BUF, W) do {                                                  \
    u16* dd_ = &Bl[BUF][pxu * 64];                                              \
    _Pragma("unroll") for (int i_ = 0; i_ < 2; ++i_) {                          \
        int qq_ = qq0 + 2 * i_;                                                 \
        *(uint4*)&dd_[(qq_ * 16)     ^ ((pxu & 7) << 3)] = make_uint4(W[i_][0], W[i_][1], W[i_][2], W[i_][3]); \
        *(uint4*)&dd_[(qq_ * 16 + 8) ^ ((pxu & 7) << 3)] = make_uint4(W[i_][4], W[i_][5], W[i_][6], W[i_][7]); \
    } } while (0)

__global__ __launch_bounds__(256) void final3_kernel(
    const u16* __restrict__ Amm, const u16* __restrict__ Afus,
    const u16* __restrict__ vbuf,
    const float* __restrict__ xin, const float* __restrict__ yin,
    const float* __restrict__ zin, float* __restrict__ out)
{
    __shared__ u16 Bl[2][128 * 64];

    const int tid = threadIdx.x;
    const int px0 = blockIdx.x * 128;
    const int o0  = blockIdx.y * 128;
    const int b   = blockIdx.z;
    const int lane = tid & 63, wid = tid >> 6;
    const int g = lane >> 4, ln = lane & 15;
    const int m0 = o0 + wid * 32;

    // B-stage mapping: this thread covers (pxu, qq0) and (pxu, qq0+2)
    const int pxu = tid & 127;
    const int qq0 = tid >> 7;      // 0 or 1

    f32x4 acc[2][8] = {};

    // prologue: stage chunk 0
    {
        u32 w0[2][8];
        LOADB_F3(0, w0);
        WRITEB_F3(0, w0);
    }
    __syncthreads();

    #pragma unroll
    for (int kc = 0; kc < 7; ++kc) {
        const int cur = kc & 1;

        // T14: issue next chunk's global loads early (held in regs across MFMA)
        u32 wn[2][8];
        if (kc < 6) {
            LOADB_F3(kc + 1, wn);
        }

        // A fragments for this chunk, direct from global (L2/L3-hot)
        short8 a[4];
        #pragma unroll
        for (int ks = 0; ks < 2; ++ks)
            #pragma unroll
            for (int fm = 0; fm < 2; ++fm) {
                int m = m0 + fm * 16 + ln;
                const u16* ap = (kc < 4)
                    ? Amm + ((size_t)b * DIM_ + m) * DIM_ + kc * 64 + ks * 32 + g * 8
                    : Afus + (size_t)m * 192 + (kc - 4) * 64 + ks * 32 + g * 8;
                a[ks * 2 + fm] = *(const short8*)ap;
            }

        // MFMA on current buffer
        #pragma unroll
        for (int ks = 0; ks < 2; ++ks)
            #pragma unroll
            for (int fn = 0; fn < 8; ++fn) {
                int p = fn * 16 + ln;
                short8 bf = *(const short8*)&Bl[cur][p * 64 + ((ks * 32 + g * 8) ^ ((p & 7) << 3))];
                acc[0][fn] = __builtin_amdgcn_mfma_f32_16x16x32_bf16(a[ks * 2 + 0], bf, acc[0][fn], 0, 0, 0);
                acc[1][fn] = __builtin_amdgcn_mfma_f32_16x16x32_bf16(a[ks * 2 + 1], bf, acc[1][fn], 0, 0, 0);
            }

        // write next buffer, single barrier per chunk
        if (kc < 6) {
            WRITEB_F3(cur ^ 1, wn);
            __syncthreads();
        }
    }

    float* op = out + (size_t)b * DIM_ * HW_;
    #pragma unroll
    for (int fm = 0; fm < 2; ++fm)
        #pragma unroll
        for (int fn = 0; fn < 8; ++fn)
            #pragma unroll
            for (int r = 0; r < 4; ++r) {
                int ch = m0 + fm * 16 + g * 4 + r;
                op[(size_t)ch * HW_ + px0 + fn * 16 + ln] = acc[fm][fn][r];
            }
}

// ---------------------------------------------------------------------------
extern "C" void kernel_launch(void* const* d_in, const int* in_sizes, int n_in,
                              void* d_out, int out_size, void* d_ws, size_t ws_size,
                              hipStream_t stream) {
    (void)in_sizes; (void)n_in; (void)out_size; (void)ws_size;

    const float* x     = (const float*)d_in[0];
    const float* y     = (const float*)d_in[1];
    const float* z     = (const float*)d_in[2];
    const float* Wq    = (const float*)d_in[3];
    const float* Wqd   = (const float*)d_in[4];
    const float* Wk    = (const float*)d_in[5];
    const float* Wkd   = (const float*)d_in[6];
    const float* Wv    = (const float*)d_in[7];
    const float* Wvd   = (const float*)d_in[8];
    const float* Wproj = (const float*)d_in[9];
    const float* Wfus  = (const float*)d_in[10];
    const float* temp  = (const float*)d_in[11];

    const size_t QELEMS = (size_t)B_ * DIM_ * HW_;   // 33.5M elems, 64 MiB bf16

    u16* preb = (u16*)d_out;                  // dead after dw
    u16* qbuf = (u16*)d_out + QELEMS;         // dead after gram
    u16* kvbuf = (u16*)d_ws;                  // k, then v
    char* wsp = (char*)d_ws + QELEMS * sizeof(u16);
    float* pgram = (float*)wsp;                       wsp += 64 * 8 * 1024 * 4;
    float* pssq  = (float*)wsp;                       wsp += 64 * 8 * 32 * 4;
    float* pssk  = (float*)wsp;                       wsp += 64 * 8 * 32 * 4;
    u16*   Amm   = (u16*)wsp;                         wsp += (size_t)B_ * DIM_ * DIM_ * 2;
    u16*   Afus  = (u16*)wsp;

    dim3 cgrid(128, B_);
    dim3 dgrid(4, DIM_, B_);

    wfus_cast_kernel<<<24, 256, 0, stream>>>(Wfus, Afus);
    conv_mfma_kernel<<<cgrid, 256, 0, stream>>>(x, Wq, preb);
    dw_kernel<<<dgrid, 256, 0, stream>>>(preb, Wqd, qbuf);
    conv_mfma_kernel<<<cgrid, 256, 0, stream>>>(y, Wk, preb);
    dw_kernel<<<dgrid, 256, 0, stream>>>(preb, Wkd, kvbuf);
    gram_mfma_kernel<<<dim3(8, 64), 256, 0, stream>>>(qbuf, kvbuf, pgram, pssq, pssk);
    softproj_kernel<<<64, 256, 0, stream>>>(pgram, pssq, pssk, Wproj, temp, Amm);
    conv_mfma_kernel<<<cgrid, 256, 0, stream>>>(z, Wv, preb);
    dw_kernel<<<dgrid, 256, 0, stream>>>(preb, Wvd, kvbuf);
    final3_kernel<<<dim3(128, 2, B_), 256, 0, stream>>>(Amm, Afus, kvbuf, x, y, z, (float*)d_out);
}